// Round 4
// baseline (1579.394 us; speedup 1.0000x reference)
//
#include <hip/hip_runtime.h>

// Chemprop BondMessagePassing, DEPTH=3, eval mode.
// R11: occupancy + MLP round.
//  - k_updm2: Wie LDS dropped (Q-phase B-frag read straight from global Wi,
//    one-time 40 scalar loads/lane). LDS 58880->52480 => 3 blocks/CU (24-wave
//    cap, was 2 blocks/16 waves). launch_bounds (512,6).
//  - k_updm1/k_updm2: depth-2 prefetch on the Sb/Hbrev gather streams.
//  - k_h0m replaces vector k_h0b_p: MFMA Q + Pb gather, NO LDS, no barriers.
//  - k_segb: 2x unrolled edge loop, dual accumulators (2x memory ILP).
// ws layout (proven >=195e6): Hb bf16 @0 (160e6) | Mf fp32 @160e6 (32e6) |
//   CSR @192e6. d_out hosts Pb(16e6)+Sb(16e6) until k_out.

#define E_EDGES 500000
#define N_NODES 50000
#define HD      160
#define BD      14
#define K1      174
#define KO      320

#define TE 64
#define KC 16
#define NC2 (HD / KC)   // 10
#define WP  (HD + 8)    // Wt stride (vector kernels)

#define TM   128        // edges per MFMA block (8 waves x 16)
#define WHP  164        // Whl padded k-stride (shorts)

typedef __attribute__((ext_vector_type(4))) short v4s;
typedef __attribute__((ext_vector_type(4))) float v4f;

// ---- bf16 helpers (RNE) ----
__device__ __forceinline__ unsigned short f2b(float v) {
    unsigned u = __float_as_uint(v);
    u += 0x7FFFu + ((u >> 16) & 1u);
    return (unsigned short)(u >> 16);
}
__device__ __forceinline__ float b2f(unsigned short h) {
    return __uint_as_float(((unsigned)h) << 16);
}

__device__ __forceinline__ v4s mdiff(ushort4 s, ushort4 r) {
    v4s a;
    a[0] = (short)f2b(b2f(s.x) - b2f(r.x));
    a[1] = (short)f2b(b2f(s.y) - b2f(r.y));
    a[2] = (short)f2b(b2f(s.z) - b2f(r.z));
    a[3] = (short)f2b(b2f(s.w) - b2f(r.w));
    return a;
}

// ---------------------------------------------------------------------------
__global__ void k_zero(float* __restrict__ p, long n)
{
    const long i = (long)blockIdx.x * 1024 + (long)threadIdx.x * 4;
    if (i + 3 < n) *(float4*)(p + i) = make_float4(0.f, 0.f, 0.f, 0.f);
}

// ---------------------------------------------------------------------------
__device__ __forceinline__
void gemm_chunk(float acc[4][10], const float At[KC][TE + 4],
                const float Wt[KC][WP], int tr, int tc)
{
    #pragma unroll
    for (int k = 0; k < KC; ++k) {
        const float4 a  = *(const float4*)&At[k][tr * 4];
        const float* wp = &Wt[k][tc * 10];
        float w[10];
        #pragma unroll
        for (int j = 0; j < 10; j += 2) {
            const float2 w2 = *(const float2*)(wp + j);
            w[j] = w2.x; w[j + 1] = w2.y;
        }
        #pragma unroll
        for (int j = 0; j < 10; ++j) {
            acc[0][j] = fmaf(a.x, w[j], acc[0][j]);
            acc[1][j] = fmaf(a.y, w[j], acc[1][j]);
            acc[2][j] = fmaf(a.z, w[j], acc[2][j]);
            acc[3][j] = fmaf(a.w, w[j], acc[3][j]);
        }
    }
}

// ============================ CSR build ====================================
__global__ void k_csr_count(const int* __restrict__ dst, int* __restrict__ cnt)
{
    const int e = blockIdx.x * 256 + threadIdx.x;
    if (e < E_EDGES) atomicAdd(&cnt[dst[e]], 1);
}

#define BPT 49
__global__ __launch_bounds__(1024)
void k_csr_scan(const int* __restrict__ cnt, int* __restrict__ ptr)
{
    __shared__ int part[1024];
    const int t  = threadIdx.x;
    const int lo = t * BPT;
    const int hi = min(lo + BPT, N_NODES);
    int s = 0;
    for (int i = lo; i < hi; ++i) s += cnt[i];
    part[t] = s;
    __syncthreads();
    for (int off = 1; off < 1024; off <<= 1) {
        int v = 0;
        if (t >= off) v = part[t - off];
        __syncthreads();
        if (t >= off) part[t] += v;
        __syncthreads();
    }
    int run = (t == 0) ? 0 : part[t - 1];
    for (int i = lo; i < hi; ++i) { ptr[i] = run; run += cnt[i]; }
    if (t == 1023) ptr[N_NODES] = part[1023];
}

__global__ void k_csr_fill(const int* __restrict__ dst, const int* __restrict__ ptr,
                           int* __restrict__ cur, int* __restrict__ eid)
{
    const int e = blockIdx.x * 256 + threadIdx.x;
    if (e < E_EDGES) {
        const int d   = dst[e];
        const int pos = atomicAdd(&cur[d], 1);
        eid[ptr[d] + pos] = e;
    }
}

// ============================ node projection ==============================
// Pb[n] = bf16(Wi_x @ x[n] + bi)   (NO relu; Wi_x = Wi[:, 0:HD], stride K1)
__global__ __launch_bounds__(256, 2)
void k_nodeproj(const float* __restrict__ x, const float* __restrict__ Wi,
                const float* __restrict__ bi, unsigned short* __restrict__ Pb)
{
    __shared__ float At[KC][TE + 4];
    __shared__ float Wt[KC][WP];

    const int  t    = threadIdx.x;
    const long base = (long)blockIdx.x * TE;
    const int  se  = t >> 2;
    const int  skq = t & 3;
    const long gn  = base + se;
    const long gnc = (gn < N_NODES) ? gn : 0;
    const float* xrow = x + gnc * HD;
    const int tr = t >> 4, tc = t & 15;

    float acc[4][10];
    #pragma unroll
    for (int i = 0; i < 4; ++i)
        #pragma unroll
        for (int j = 0; j < 10; ++j) acc[i][j] = 0.f;

    for (int c = 0; c < NC2; ++c) {
        const int k0 = c * KC;
        __syncthreads();
        {
            const float4 v = *(const float4*)(xrow + k0 + skq * 4);
            At[skq * 4 + 0][se] = v.x;
            At[skq * 4 + 1][se] = v.y;
            At[skq * 4 + 2][se] = v.z;
            At[skq * 4 + 3][se] = v.w;
        }
        for (int i = t; i < HD * KC; i += 256) {
            const int kk = i & (KC - 1);
            const int h  = i >> 4;
            Wt[kk][h] = Wi[h * K1 + k0 + kk];
        }
        __syncthreads();
        gemm_chunk(acc, At, Wt, tr, tc);
    }
    #pragma unroll
    for (int i = 0; i < 4; ++i) {
        const long n = base + tr * 4 + i;
        if (n >= N_NODES) break;
        unsigned short* pp = Pb + n * HD + tc * 10;
        #pragma unroll
        for (int j = 0; j < 10; j += 2) {
            const float v0 = acc[i][j]     + bi[tc * 10 + j];
            const float v1 = acc[i][j + 1] + bi[tc * 10 + j + 1];
            *(ushort2*)(pp + j) = make_ushort2(f2b(v0), f2b(v1));
        }
    }
}

// ============================ H0 (MFMA, no LDS) ============================
// Hb[e] = bf16(relu(Pb[src[e]] + ea[e] @ Wi_e^T)), 16 edges/wave.
__global__ __launch_bounds__(512, 6)
void k_h0m(const float* __restrict__ ea, const int* __restrict__ src,
           const float* __restrict__ Wi, const unsigned short* __restrict__ Pb,
           unsigned short* __restrict__ Hb)
{
    const int  t    = threadIdx.x;
    const int  w    = t >> 6;
    const int  lane = t & 63;
    const int  cl   = lane & 15;
    const int  kq   = lane >> 4;
    const long base = (long)blockIdx.x * TM + w * 16;

    const long eA  = base + cl;
    const long eAs = (eA < E_EDGES) ? eA : 0;

    // A-frag from ea row (k' = kq*4+j; guard k' < BD without OOB reads)
    v4s aq;
    {
        const float* earow = ea + eAs * BD;
        if (kq < 3) {
            #pragma unroll
            for (int j = 0; j < 4; ++j) aq[j] = (short)f2b(earow[kq * 4 + j]);
        } else {
            aq[0] = (short)f2b(earow[12]);
            aq[1] = (short)f2b(earow[13]);
            aq[2] = 0; aq[3] = 0;
        }
    }
    int srcC[4];
    #pragma unroll
    for (int rr = 0; rr < 4; ++rr) {
        const long e = base + kq * 4 + rr;
        srcC[rr] = src[(e < E_EDGES) ? e : 0];
    }

    #pragma unroll
    for (int n = 0; n < 10; ++n) {
        const int col = n * 16 + cl;
        // B-frag straight from global Wi (cols HD..HD+13 of row `col`)
        v4s bq;
        {
            const float* wr = Wi + (long)col * K1 + HD + kq * 4;
            if (kq < 3) {
                #pragma unroll
                for (int j = 0; j < 4; ++j) bq[j] = (short)f2b(wr[j]);
            } else {
                bq[0] = (short)f2b(wr[0]);
                bq[1] = (short)f2b(wr[1]);
                bq[2] = 0; bq[3] = 0;
            }
        }
        const v4f q = __builtin_amdgcn_mfma_f32_16x16x16bf16_1k(
                          aq, bq, (v4f){0.f, 0.f, 0.f, 0.f}, 0, 0, 0);
        #pragma unroll
        for (int rr = 0; rr < 4; ++rr) {
            const long e = base + kq * 4 + rr;
            if (e < E_EDGES) {
                const float pv = b2f(Pb[(long)srcC[rr] * HD + col]);
                float v = pv + q[rr];
                v = v > 0.f ? v : 0.f;
                Hb[e * HD + col] = f2b(v);
            }
        }
    }
}

// ============================ segment sum ==================================
// FINAL=0: write bf16 Sb. FINAL=1: write fp32 S with sum==0 -> x fallback.
// 2x unrolled edge loop (dual accumulators -> 2x memory ILP).
template <int FINAL>
__global__ void k_segb(const unsigned short* __restrict__ Hb,
                       const int* __restrict__ ptr, const int* __restrict__ eid,
                       const float* __restrict__ x,
                       unsigned short* __restrict__ Sb, float* __restrict__ S)
{
    const int  lane = threadIdx.x & 63;
    const int  w    = threadIdx.x >> 6;
    const long n    = (long)blockIdx.x * 4 + w;
    if (n >= N_NODES) return;
    const int p0 = ptr[n], p1 = ptr[n + 1];
    float a0 = 0.f, a1 = 0.f, a2 = 0.f;
    float c0 = 0.f, c1 = 0.f, c2 = 0.f;
    int i = p0;
    for (; i + 2 <= p1; i += 2) {
        const int e0 = eid[i], e1 = eid[i + 1];
        const unsigned short* r0 = Hb + (long)e0 * HD;
        const unsigned short* r1 = Hb + (long)e1 * HD;
        a0 += b2f(r0[lane]);
        c0 += b2f(r1[lane]);
        a1 += b2f(r0[64 + lane]);
        c1 += b2f(r1[64 + lane]);
        if (lane < 32) {
            a2 += b2f(r0[128 + lane]);
            c2 += b2f(r1[128 + lane]);
        }
    }
    if (i < p1) {
        const unsigned short* r0 = Hb + (long)eid[i] * HD;
        a0 += b2f(r0[lane]);
        a1 += b2f(r0[64 + lane]);
        if (lane < 32) a2 += b2f(r0[128 + lane]);
    }
    a0 += c0; a1 += c1; a2 += c2;

    const long sb = n * HD;
    if (FINAL) {
        float s = a0 + a1 + a2;
        #pragma unroll
        for (int off = 32; off > 0; off >>= 1) s += __shfl_xor(s, off, 64);
        if (s == 0.f) {
            S[sb + lane]      = x[sb + lane];
            S[sb + 64 + lane] = x[sb + 64 + lane];
            if (lane < 32) S[sb + 128 + lane] = x[sb + 128 + lane];
            return;
        }
        S[sb + lane]      = a0;
        S[sb + 64 + lane] = a1;
        if (lane < 32) S[sb + 128 + lane] = a2;
    } else {
        Sb[sb + lane]      = f2b(a0);
        Sb[sb + 64 + lane] = f2b(a1);
        if (lane < 32) Sb[sb + 128 + lane] = f2b(a2);
    }
}

// ============================ MFMA update, iter 1 ==========================
// Hb[e] = bf16(relu(Hb[e] + Wh @ (Sb[src[e]] - Hb[e^1]) + bh))
// (Hb still holds H0 = h0.)  8 waves x 16 edges; no barriers after staging.
__global__ __launch_bounds__(512, 6)
void k_updm1(const unsigned short* __restrict__ Sb,
             const int* __restrict__ src,
             const float* __restrict__ Wh, const float* __restrict__ bh,
             unsigned short* __restrict__ Hb)
{
    __shared__ unsigned short Whl[HD * WHP];   // 52480 B, [h][k] bf16

    const int t = threadIdx.x;
    for (int i = t * 4; i < HD * HD; i += 2048) {
        const int h = i / HD, k = i % HD;
        const float4 wv = *(const float4*)(Wh + h * HD + k);
        *(ushort4*)&Whl[h * WHP + k] =
            make_ushort4(f2b(wv.x), f2b(wv.y), f2b(wv.z), f2b(wv.w));
    }
    __syncthreads();

    const int  w    = t >> 6;
    const int  lane = t & 63;
    const int  cl   = lane & 15;     // A-row / B-col / C-col selector
    const int  kq   = lane >> 4;     // k-group 0..3
    const long base = (long)blockIdx.x * TM + w * 16;

    const long eA  = base + cl;
    const long eAs = (eA < E_EDGES) ? eA : 0;
    const int  sA  = src[eAs];
    const unsigned short* sbrow = Sb + (long)sA * HD + kq * 4;
    const unsigned short* rvrow = Hb + (eAs ^ 1) * HD + kq * 4;

    v4f acc[10];
    #pragma unroll
    for (int n = 0; n < 10; ++n) acc[n] = (v4f){0.f, 0.f, 0.f, 0.f};

    // depth-2 prefetch of the gather streams
    ushort4 ps0 = *(const ushort4*)(sbrow);
    ushort4 pr0 = *(const ushort4*)(rvrow);
    ushort4 ps1 = *(const ushort4*)(sbrow + KC);
    ushort4 pr1 = *(const ushort4*)(rvrow + KC);
    #pragma unroll
    for (int c = 0; c < 10; ++c) {
        const v4s a = mdiff(ps0, pr0);
        ps0 = ps1; pr0 = pr1;
        if (c + 2 < 10) {
            ps1 = *(const ushort4*)(sbrow + (c + 2) * KC);
            pr1 = *(const ushort4*)(rvrow + (c + 2) * KC);
        }
        #pragma unroll
        for (int n = 0; n < 10; ++n) {
            const v4s b = *(const v4s*)&Whl[(n * 16 + cl) * WHP + c * KC + kq * 4];
            acc[n] = __builtin_amdgcn_mfma_f32_16x16x16bf16_1k(a, b, acc[n], 0, 0, 0);
        }
    }

    #pragma unroll
    for (int n = 0; n < 10; ++n) {
        const int col = n * 16 + cl;
        const float bb = bh[col];
        #pragma unroll
        for (int rr = 0; rr < 4; ++rr) {
            const long e = base + kq * 4 + rr;
            if (e < E_EDGES) {
                unsigned short* hp = Hb + e * HD + col;
                float v = b2f(*hp) + acc[n][rr] + bb;
                v = v > 0.f ? v : 0.f;
                *hp = f2b(v);
            }
        }
    }
}

// ============================ MFMA update, iter 2 ==========================
// h0 = relu(Pb[src] + ea @ Wi_e^T)  (Q MFMA, B-frag from global Wi)
// Hb[e] = bf16(relu(h0 + Wh @ (Sb[src[e]] - Hb[e^1]) + bh))
__global__ __launch_bounds__(512, 6)
void k_updm2(const unsigned short* __restrict__ Sb,
             const float* __restrict__ ea, const int* __restrict__ src,
             const float* __restrict__ Wi, const float* __restrict__ Wh,
             const float* __restrict__ bh,
             const unsigned short* __restrict__ Pb,
             unsigned short* __restrict__ Hb)
{
    __shared__ unsigned short Whl[HD * WHP];    // 52480 B -> 3 blocks/CU

    const int t = threadIdx.x;
    for (int i = t * 4; i < HD * HD; i += 2048) {
        const int h = i / HD, k = i % HD;
        const float4 wv = *(const float4*)(Wh + h * HD + k);
        *(ushort4*)&Whl[h * WHP + k] =
            make_ushort4(f2b(wv.x), f2b(wv.y), f2b(wv.z), f2b(wv.w));
    }
    __syncthreads();

    const int  w    = t >> 6;
    const int  lane = t & 63;
    const int  cl   = lane & 15;
    const int  kq   = lane >> 4;
    const long base = (long)blockIdx.x * TM + w * 16;

    const long eA  = base + cl;
    const long eAs = (eA < E_EDGES) ? eA : 0;
    const int  sA  = src[eAs];
    const unsigned short* sbrow = Sb + (long)sA * HD + kq * 4;
    const unsigned short* rvrow = Hb + (eAs ^ 1) * HD + kq * 4;

    // ---- Q: A-frag from ea row (guard k' < BD without OOB reads) ----
    v4s aq;
    {
        const float* earow = ea + eAs * BD;
        if (kq < 3) {
            #pragma unroll
            for (int j = 0; j < 4; ++j) aq[j] = (short)f2b(earow[kq * 4 + j]);
        } else {
            aq[0] = (short)f2b(earow[12]);
            aq[1] = (short)f2b(earow[13]);
            aq[2] = 0; aq[3] = 0;
        }
    }
    int srcC[4];
    #pragma unroll
    for (int rr = 0; rr < 4; ++rr) {
        const long e = base + kq * 4 + rr;
        srcC[rr] = src[(e < E_EDGES) ? e : 0];
    }

    // h0 = relu(Pb gather + Q), B-frag from global Wi
    float h0[10][4];
    #pragma unroll
    for (int n = 0; n < 10; ++n) {
        const int col = n * 16 + cl;
        v4s bq;
        {
            const float* wr = Wi + (long)col * K1 + HD + kq * 4;
            if (kq < 3) {
                #pragma unroll
                for (int j = 0; j < 4; ++j) bq[j] = (short)f2b(wr[j]);
            } else {
                bq[0] = (short)f2b(wr[0]);
                bq[1] = (short)f2b(wr[1]);
                bq[2] = 0; bq[3] = 0;
            }
        }
        const v4f q = __builtin_amdgcn_mfma_f32_16x16x16bf16_1k(
                          aq, bq, (v4f){0.f, 0.f, 0.f, 0.f}, 0, 0, 0);
        #pragma unroll
        for (int rr = 0; rr < 4; ++rr) {
            const float pv = b2f(Pb[(long)srcC[rr] * HD + col]);
            const float v  = pv + q[rr];
            h0[n][rr] = v > 0.f ? v : 0.f;
        }
    }

    // ---- Wh @ (Sb - Hbrev), depth-2 prefetch ----
    v4f acc[10];
    #pragma unroll
    for (int n = 0; n < 10; ++n) acc[n] = (v4f){0.f, 0.f, 0.f, 0.f};

    ushort4 ps0 = *(const ushort4*)(sbrow);
    ushort4 pr0 = *(const ushort4*)(rvrow);
    ushort4 ps1 = *(const ushort4*)(sbrow + KC);
    ushort4 pr1 = *(const ushort4*)(rvrow + KC);
    #pragma unroll
    for (int c = 0; c < 10; ++c) {
        const v4s a = mdiff(ps0, pr0);
        ps0 = ps1; pr0 = pr1;
        if (c + 2 < 10) {
            ps1 = *(const ushort4*)(sbrow + (c + 2) * KC);
            pr1 = *(const ushort4*)(rvrow + (c + 2) * KC);
        }
        #pragma unroll
        for (int n = 0; n < 10; ++n) {
            const v4s b = *(const v4s*)&Whl[(n * 16 + cl) * WHP + c * KC + kq * 4];
            acc[n] = __builtin_amdgcn_mfma_f32_16x16x16bf16_1k(a, b, acc[n], 0, 0, 0);
        }
    }

    #pragma unroll
    for (int n = 0; n < 10; ++n) {
        const int col = n * 16 + cl;
        const float bb = bh[col];
        #pragma unroll
        for (int rr = 0; rr < 4; ++rr) {
            const long e = base + kq * 4 + rr;
            if (e < E_EDGES) {
                float v = h0[n][rr] + acc[n][rr] + bb;
                v = v > 0.f ? v : 0.f;
                Hb[e * HD + col] = f2b(v);
            }
        }
    }
}

// ============================ output =======================================
__global__ __launch_bounds__(256, 2)
void k_out(const float* __restrict__ x, const float* __restrict__ Mg,
           const float* __restrict__ Wo, const float* __restrict__ bo,
           float* __restrict__ out)
{
    __shared__ float At[KC][TE + 4];
    __shared__ float Wt[KC][WP];

    const int  t    = threadIdx.x;
    const long base = (long)blockIdx.x * TE;
    const int  se  = t >> 2;
    const int  skq = t & 3;
    const long gn  = base + se;
    const bool ev  = gn < N_NODES;
    const long gnc = ev ? gn : 0;
    const float* xrow = x  + gnc * HD;
    const float* mrow = Mg + gnc * HD;
    const int tr = t >> 4, tc = t & 15;

    float acc[4][10];
    #pragma unroll
    for (int i = 0; i < 4; ++i)
        #pragma unroll
        for (int j = 0; j < 10; ++j) acc[i][j] = 0.f;

    for (int c = 0; c < KO / KC; ++c) {
        const int k0 = c * KC;
        __syncthreads();
        {
            const int kb = k0 + skq * 4;
            const float4 v = (kb < HD) ? *(const float4*)(xrow + kb)
                                       : *(const float4*)(mrow + (kb - HD));
            At[skq * 4 + 0][se] = v.x;
            At[skq * 4 + 1][se] = v.y;
            At[skq * 4 + 2][se] = v.z;
            At[skq * 4 + 3][se] = v.w;
        }
        for (int i = t; i < HD * KC; i += 256) {
            const int kk = i & (KC - 1);
            const int h  = i >> 4;
            Wt[kk][h] = Wo[h * KO + k0 + kk];
        }
        __syncthreads();
        gemm_chunk(acc, At, Wt, tr, tc);
    }
    #pragma unroll
    for (int i = 0; i < 4; ++i) {
        const long n = base + tr * 4 + i;
        if (n >= N_NODES) break;
        float* op = out + n * HD + tc * 10;
        #pragma unroll
        for (int j = 0; j < 10; j += 2) {
            float v0 = acc[i][j]     + bo[tc * 10 + j];
            float v1 = acc[i][j + 1] + bo[tc * 10 + j + 1];
            v0 = v0 > 0.f ? v0 : 0.f;
            v1 = v1 > 0.f ? v1 : 0.f;
            *(float2*)(op + j) = make_float2(v0, v1);
        }
    }
}

// ---------------------------------------------------------------------------
extern "C" void kernel_launch(void* const* d_in, const int* in_sizes, int n_in,
                              void* d_out, int out_size, void* d_ws, size_t ws_size,
                              hipStream_t stream)
{
    const float* x  = (const float*)d_in[0];
    const float* ea = (const float*)d_in[1];
    const int*   ei = (const int*)d_in[2];
    const float* Wi = (const float*)d_in[4];
    const float* bi = (const float*)d_in[5];
    const float* Wh = (const float*)d_in[6];
    const float* bh = (const float*)d_in[7];
    const float* Wo = (const float*)d_in[8];
    const float* bo = (const float*)d_in[9];
    float* out = (float*)d_out;

    const int* src = ei;
    const int* dst = ei + E_EDGES;

    const int gM  = (E_EDGES + TM - 1) / TM;      // 3907
    const int gN  = (N_NODES + TE - 1) / TE;      // 782
    const int gF  = (N_NODES + 3) / 4;            // 12500
    const int gEe = (E_EDGES + 255) / 256;        // 1954

    // ws: Hb bf16 (160e6) | Mf fp32 (32e6) | CSR (~2.6e6)  -> 194.6e6 proven
    char* w = (char*)d_ws;
    unsigned short* Hb = (unsigned short*)(w);
    float* Mf  = (float*)(w + 160000000);
    int*   ptr = (int*)  (w + 192000000);
    int*   cnt = (int*)  (w + 192200016);
    int*   cur = (int*)  (w + 192400016);
    int*   eid = (int*)  (w + 192600016);
    // d_out hosts Pb (16e6) + Sb (16e6) until k_out.
    unsigned short* Pb = (unsigned short*)d_out;
    unsigned short* Sb = (unsigned short*)((char*)d_out + 16000000);

    k_zero<<<(100000 + 1023) / 1024, 256, 0, stream>>>((float*)cnt, 100000);
    k_csr_count<<<gEe, 256, 0, stream>>>(dst, cnt);
    k_csr_scan<<<1, 1024, 0, stream>>>(cnt, ptr);
    k_csr_fill<<<gEe, 256, 0, stream>>>(dst, ptr, cur, eid);

    k_nodeproj<<<gN, 256, 0, stream>>>(x, Wi, bi, Pb);
    k_h0m<<<gM, 512, 0, stream>>>(ea, src, Wi, Pb, Hb);                   // H0
    k_segb<0><<<gF, 256, 0, stream>>>(Hb, ptr, eid, x, Sb, nullptr);      // S0
    k_updm1<<<gM, 512, 0, stream>>>(Sb, src, Wh, bh, Hb);                 // H1
    k_segb<0><<<gF, 256, 0, stream>>>(Hb, ptr, eid, x, Sb, nullptr);      // S1
    k_updm2<<<gM, 512, 0, stream>>>(Sb, ea, src, Wi, Wh, bh, Pb, Hb);     // H2
    k_segb<1><<<gF, 256, 0, stream>>>(Hb, ptr, eid, x, nullptr, Mf);      // M
    k_out<<<gN, 256, 0, stream>>>(x, Mf, Wo, bo, out);
}

// Round 5
// 1098.003 us; speedup vs baseline: 1.4384x; 1.4384x over previous
//
#include <hip/hip_runtime.h>

// Chemprop BondMessagePassing, DEPTH=3, eval mode.
// R12: spill-fix round (R11 post-mortem: launch_bounds(512,6) + h0[40] array
//   = 40-reg scratch spill, WRITE 263MB->1.03GB, updm2 208->690us).
//  - k_updm2: DEFERRED-h0 restructure. Wh K-loop first (acc in 40 AGPR),
//    then per-n epilogue: Q-MFMA (B-frag from global Wi) + Pb gather + fused
//    relu/store. No h0 array -> peak regs ~40 AGPR + ~40 arch <= 85 cap of
//    (512,6) => 3 blocks/CU (24 waves). K-loop prefetch depth-1 (reg slack).
//  - k_updm1 unchanged (fits 85: acc 40 + ~30 arch; ran fine R3/R4).
//  - All other kernels byte-identical to R11.
// ws layout (proven >=195e6): Hb bf16 @0 (160e6) | Mf fp32 @160e6 (32e6) |
//   CSR @192e6. d_out hosts Pb(16e6)+Sb(16e6) until k_out.

#define E_EDGES 500000
#define N_NODES 50000
#define HD      160
#define BD      14
#define K1      174
#define KO      320

#define TE 64
#define KC 16
#define NC2 (HD / KC)   // 10
#define WP  (HD + 8)    // Wt stride (vector kernels)

#define TM   128        // edges per MFMA block (8 waves x 16)
#define WHP  164        // Whl padded k-stride (shorts)

typedef __attribute__((ext_vector_type(4))) short v4s;
typedef __attribute__((ext_vector_type(4))) float v4f;

// ---- bf16 helpers (RNE) ----
__device__ __forceinline__ unsigned short f2b(float v) {
    unsigned u = __float_as_uint(v);
    u += 0x7FFFu + ((u >> 16) & 1u);
    return (unsigned short)(u >> 16);
}
__device__ __forceinline__ float b2f(unsigned short h) {
    return __uint_as_float(((unsigned)h) << 16);
}

__device__ __forceinline__ v4s mdiff(ushort4 s, ushort4 r) {
    v4s a;
    a[0] = (short)f2b(b2f(s.x) - b2f(r.x));
    a[1] = (short)f2b(b2f(s.y) - b2f(r.y));
    a[2] = (short)f2b(b2f(s.z) - b2f(r.z));
    a[3] = (short)f2b(b2f(s.w) - b2f(r.w));
    return a;
}

// ---------------------------------------------------------------------------
__global__ void k_zero(float* __restrict__ p, long n)
{
    const long i = (long)blockIdx.x * 1024 + (long)threadIdx.x * 4;
    if (i + 3 < n) *(float4*)(p + i) = make_float4(0.f, 0.f, 0.f, 0.f);
}

// ---------------------------------------------------------------------------
__device__ __forceinline__
void gemm_chunk(float acc[4][10], const float At[KC][TE + 4],
                const float Wt[KC][WP], int tr, int tc)
{
    #pragma unroll
    for (int k = 0; k < KC; ++k) {
        const float4 a  = *(const float4*)&At[k][tr * 4];
        const float* wp = &Wt[k][tc * 10];
        float w[10];
        #pragma unroll
        for (int j = 0; j < 10; j += 2) {
            const float2 w2 = *(const float2*)(wp + j);
            w[j] = w2.x; w[j + 1] = w2.y;
        }
        #pragma unroll
        for (int j = 0; j < 10; ++j) {
            acc[0][j] = fmaf(a.x, w[j], acc[0][j]);
            acc[1][j] = fmaf(a.y, w[j], acc[1][j]);
            acc[2][j] = fmaf(a.z, w[j], acc[2][j]);
            acc[3][j] = fmaf(a.w, w[j], acc[3][j]);
        }
    }
}

// ============================ CSR build ====================================
__global__ void k_csr_count(const int* __restrict__ dst, int* __restrict__ cnt)
{
    const int e = blockIdx.x * 256 + threadIdx.x;
    if (e < E_EDGES) atomicAdd(&cnt[dst[e]], 1);
}

#define BPT 49
__global__ __launch_bounds__(1024)
void k_csr_scan(const int* __restrict__ cnt, int* __restrict__ ptr)
{
    __shared__ int part[1024];
    const int t  = threadIdx.x;
    const int lo = t * BPT;
    const int hi = min(lo + BPT, N_NODES);
    int s = 0;
    for (int i = lo; i < hi; ++i) s += cnt[i];
    part[t] = s;
    __syncthreads();
    for (int off = 1; off < 1024; off <<= 1) {
        int v = 0;
        if (t >= off) v = part[t - off];
        __syncthreads();
        if (t >= off) part[t] += v;
        __syncthreads();
    }
    int run = (t == 0) ? 0 : part[t - 1];
    for (int i = lo; i < hi; ++i) { ptr[i] = run; run += cnt[i]; }
    if (t == 1023) ptr[N_NODES] = part[1023];
}

__global__ void k_csr_fill(const int* __restrict__ dst, const int* __restrict__ ptr,
                           int* __restrict__ cur, int* __restrict__ eid)
{
    const int e = blockIdx.x * 256 + threadIdx.x;
    if (e < E_EDGES) {
        const int d   = dst[e];
        const int pos = atomicAdd(&cur[d], 1);
        eid[ptr[d] + pos] = e;
    }
}

// ============================ node projection ==============================
// Pb[n] = bf16(Wi_x @ x[n] + bi)   (NO relu; Wi_x = Wi[:, 0:HD], stride K1)
__global__ __launch_bounds__(256, 2)
void k_nodeproj(const float* __restrict__ x, const float* __restrict__ Wi,
                const float* __restrict__ bi, unsigned short* __restrict__ Pb)
{
    __shared__ float At[KC][TE + 4];
    __shared__ float Wt[KC][WP];

    const int  t    = threadIdx.x;
    const long base = (long)blockIdx.x * TE;
    const int  se  = t >> 2;
    const int  skq = t & 3;
    const long gn  = base + se;
    const long gnc = (gn < N_NODES) ? gn : 0;
    const float* xrow = x + gnc * HD;
    const int tr = t >> 4, tc = t & 15;

    float acc[4][10];
    #pragma unroll
    for (int i = 0; i < 4; ++i)
        #pragma unroll
        for (int j = 0; j < 10; ++j) acc[i][j] = 0.f;

    for (int c = 0; c < NC2; ++c) {
        const int k0 = c * KC;
        __syncthreads();
        {
            const float4 v = *(const float4*)(xrow + k0 + skq * 4);
            At[skq * 4 + 0][se] = v.x;
            At[skq * 4 + 1][se] = v.y;
            At[skq * 4 + 2][se] = v.z;
            At[skq * 4 + 3][se] = v.w;
        }
        for (int i = t; i < HD * KC; i += 256) {
            const int kk = i & (KC - 1);
            const int h  = i >> 4;
            Wt[kk][h] = Wi[h * K1 + k0 + kk];
        }
        __syncthreads();
        gemm_chunk(acc, At, Wt, tr, tc);
    }
    #pragma unroll
    for (int i = 0; i < 4; ++i) {
        const long n = base + tr * 4 + i;
        if (n >= N_NODES) break;
        unsigned short* pp = Pb + n * HD + tc * 10;
        #pragma unroll
        for (int j = 0; j < 10; j += 2) {
            const float v0 = acc[i][j]     + bi[tc * 10 + j];
            const float v1 = acc[i][j + 1] + bi[tc * 10 + j + 1];
            *(ushort2*)(pp + j) = make_ushort2(f2b(v0), f2b(v1));
        }
    }
}

// ============================ H0 (MFMA, no LDS) ============================
// Hb[e] = bf16(relu(Pb[src[e]] + ea[e] @ Wi_e^T)), 16 edges/wave.
__global__ __launch_bounds__(512, 6)
void k_h0m(const float* __restrict__ ea, const int* __restrict__ src,
           const float* __restrict__ Wi, const unsigned short* __restrict__ Pb,
           unsigned short* __restrict__ Hb)
{
    const int  t    = threadIdx.x;
    const int  w    = t >> 6;
    const int  lane = t & 63;
    const int  cl   = lane & 15;
    const int  kq   = lane >> 4;
    const long base = (long)blockIdx.x * TM + w * 16;

    const long eA  = base + cl;
    const long eAs = (eA < E_EDGES) ? eA : 0;

    // A-frag from ea row (k' = kq*4+j; guard k' < BD without OOB reads)
    v4s aq;
    {
        const float* earow = ea + eAs * BD;
        if (kq < 3) {
            #pragma unroll
            for (int j = 0; j < 4; ++j) aq[j] = (short)f2b(earow[kq * 4 + j]);
        } else {
            aq[0] = (short)f2b(earow[12]);
            aq[1] = (short)f2b(earow[13]);
            aq[2] = 0; aq[3] = 0;
        }
    }
    int srcC[4];
    #pragma unroll
    for (int rr = 0; rr < 4; ++rr) {
        const long e = base + kq * 4 + rr;
        srcC[rr] = src[(e < E_EDGES) ? e : 0];
    }

    #pragma unroll
    for (int n = 0; n < 10; ++n) {
        const int col = n * 16 + cl;
        // B-frag straight from global Wi (cols HD..HD+13 of row `col`)
        v4s bq;
        {
            const float* wr = Wi + (long)col * K1 + HD + kq * 4;
            if (kq < 3) {
                #pragma unroll
                for (int j = 0; j < 4; ++j) bq[j] = (short)f2b(wr[j]);
            } else {
                bq[0] = (short)f2b(wr[0]);
                bq[1] = (short)f2b(wr[1]);
                bq[2] = 0; bq[3] = 0;
            }
        }
        const v4f q = __builtin_amdgcn_mfma_f32_16x16x16bf16_1k(
                          aq, bq, (v4f){0.f, 0.f, 0.f, 0.f}, 0, 0, 0);
        #pragma unroll
        for (int rr = 0; rr < 4; ++rr) {
            const long e = base + kq * 4 + rr;
            if (e < E_EDGES) {
                const float pv = b2f(Pb[(long)srcC[rr] * HD + col]);
                float v = pv + q[rr];
                v = v > 0.f ? v : 0.f;
                Hb[e * HD + col] = f2b(v);
            }
        }
    }
}

// ============================ segment sum ==================================
// FINAL=0: write bf16 Sb. FINAL=1: write fp32 S with sum==0 -> x fallback.
// 2x unrolled edge loop (dual accumulators -> 2x memory ILP).
template <int FINAL>
__global__ void k_segb(const unsigned short* __restrict__ Hb,
                       const int* __restrict__ ptr, const int* __restrict__ eid,
                       const float* __restrict__ x,
                       unsigned short* __restrict__ Sb, float* __restrict__ S)
{
    const int  lane = threadIdx.x & 63;
    const int  w    = threadIdx.x >> 6;
    const long n    = (long)blockIdx.x * 4 + w;
    if (n >= N_NODES) return;
    const int p0 = ptr[n], p1 = ptr[n + 1];
    float a0 = 0.f, a1 = 0.f, a2 = 0.f;
    float c0 = 0.f, c1 = 0.f, c2 = 0.f;
    int i = p0;
    for (; i + 2 <= p1; i += 2) {
        const int e0 = eid[i], e1 = eid[i + 1];
        const unsigned short* r0 = Hb + (long)e0 * HD;
        const unsigned short* r1 = Hb + (long)e1 * HD;
        a0 += b2f(r0[lane]);
        c0 += b2f(r1[lane]);
        a1 += b2f(r0[64 + lane]);
        c1 += b2f(r1[64 + lane]);
        if (lane < 32) {
            a2 += b2f(r0[128 + lane]);
            c2 += b2f(r1[128 + lane]);
        }
    }
    if (i < p1) {
        const unsigned short* r0 = Hb + (long)eid[i] * HD;
        a0 += b2f(r0[lane]);
        a1 += b2f(r0[64 + lane]);
        if (lane < 32) a2 += b2f(r0[128 + lane]);
    }
    a0 += c0; a1 += c1; a2 += c2;

    const long sb = n * HD;
    if (FINAL) {
        float s = a0 + a1 + a2;
        #pragma unroll
        for (int off = 32; off > 0; off >>= 1) s += __shfl_xor(s, off, 64);
        if (s == 0.f) {
            S[sb + lane]      = x[sb + lane];
            S[sb + 64 + lane] = x[sb + 64 + lane];
            if (lane < 32) S[sb + 128 + lane] = x[sb + 128 + lane];
            return;
        }
        S[sb + lane]      = a0;
        S[sb + 64 + lane] = a1;
        if (lane < 32) S[sb + 128 + lane] = a2;
    } else {
        Sb[sb + lane]      = f2b(a0);
        Sb[sb + 64 + lane] = f2b(a1);
        if (lane < 32) Sb[sb + 128 + lane] = f2b(a2);
    }
}

// ============================ MFMA update, iter 1 ==========================
// Hb[e] = bf16(relu(Hb[e] + Wh @ (Sb[src[e]] - Hb[e^1]) + bh))
// (Hb still holds H0 = h0.)  8 waves x 16 edges; no barriers after staging.
__global__ __launch_bounds__(512, 6)
void k_updm1(const unsigned short* __restrict__ Sb,
             const int* __restrict__ src,
             const float* __restrict__ Wh, const float* __restrict__ bh,
             unsigned short* __restrict__ Hb)
{
    __shared__ unsigned short Whl[HD * WHP];   // 52480 B, [h][k] bf16

    const int t = threadIdx.x;
    for (int i = t * 4; i < HD * HD; i += 2048) {
        const int h = i / HD, k = i % HD;
        const float4 wv = *(const float4*)(Wh + h * HD + k);
        *(ushort4*)&Whl[h * WHP + k] =
            make_ushort4(f2b(wv.x), f2b(wv.y), f2b(wv.z), f2b(wv.w));
    }
    __syncthreads();

    const int  w    = t >> 6;
    const int  lane = t & 63;
    const int  cl   = lane & 15;     // A-row / B-col / C-col selector
    const int  kq   = lane >> 4;     // k-group 0..3
    const long base = (long)blockIdx.x * TM + w * 16;

    const long eA  = base + cl;
    const long eAs = (eA < E_EDGES) ? eA : 0;
    const int  sA  = src[eAs];
    const unsigned short* sbrow = Sb + (long)sA * HD + kq * 4;
    const unsigned short* rvrow = Hb + (eAs ^ 1) * HD + kq * 4;

    v4f acc[10];
    #pragma unroll
    for (int n = 0; n < 10; ++n) acc[n] = (v4f){0.f, 0.f, 0.f, 0.f};

    // depth-2 prefetch of the gather streams
    ushort4 ps0 = *(const ushort4*)(sbrow);
    ushort4 pr0 = *(const ushort4*)(rvrow);
    ushort4 ps1 = *(const ushort4*)(sbrow + KC);
    ushort4 pr1 = *(const ushort4*)(rvrow + KC);
    #pragma unroll
    for (int c = 0; c < 10; ++c) {
        const v4s a = mdiff(ps0, pr0);
        ps0 = ps1; pr0 = pr1;
        if (c + 2 < 10) {
            ps1 = *(const ushort4*)(sbrow + (c + 2) * KC);
            pr1 = *(const ushort4*)(rvrow + (c + 2) * KC);
        }
        #pragma unroll
        for (int n = 0; n < 10; ++n) {
            const v4s b = *(const v4s*)&Whl[(n * 16 + cl) * WHP + c * KC + kq * 4];
            acc[n] = __builtin_amdgcn_mfma_f32_16x16x16bf16_1k(a, b, acc[n], 0, 0, 0);
        }
    }

    #pragma unroll
    for (int n = 0; n < 10; ++n) {
        const int col = n * 16 + cl;
        const float bb = bh[col];
        #pragma unroll
        for (int rr = 0; rr < 4; ++rr) {
            const long e = base + kq * 4 + rr;
            if (e < E_EDGES) {
                unsigned short* hp = Hb + e * HD + col;
                float v = b2f(*hp) + acc[n][rr] + bb;
                v = v > 0.f ? v : 0.f;
                *hp = f2b(v);
            }
        }
    }
}

// ============================ MFMA update, iter 2 ==========================
// DEFERRED-h0: Wh K-loop first (acc in AGPR), then per-n epilogue computes
// q = ea @ Wi_e^T (MFMA, B-frag from global Wi), h0 = relu(Pb[src]+q), and
// stores relu(h0 + acc + bh). No h0 array -> fits 85-reg cap of (512,6).
__global__ __launch_bounds__(512, 6)
void k_updm2(const unsigned short* __restrict__ Sb,
             const float* __restrict__ ea, const int* __restrict__ src,
             const float* __restrict__ Wi, const float* __restrict__ Wh,
             const float* __restrict__ bh,
             const unsigned short* __restrict__ Pb,
             unsigned short* __restrict__ Hb)
{
    __shared__ unsigned short Whl[HD * WHP];    // 52480 B -> 3 blocks/CU

    const int t = threadIdx.x;
    for (int i = t * 4; i < HD * HD; i += 2048) {
        const int h = i / HD, k = i % HD;
        const float4 wv = *(const float4*)(Wh + h * HD + k);
        *(ushort4*)&Whl[h * WHP + k] =
            make_ushort4(f2b(wv.x), f2b(wv.y), f2b(wv.z), f2b(wv.w));
    }
    __syncthreads();

    const int  w    = t >> 6;
    const int  lane = t & 63;
    const int  cl   = lane & 15;
    const int  kq   = lane >> 4;
    const long base = (long)blockIdx.x * TM + w * 16;

    const long eA  = base + cl;
    const long eAs = (eA < E_EDGES) ? eA : 0;
    const int  sA  = src[eAs];
    const unsigned short* sbrow = Sb + (long)sA * HD + kq * 4;
    const unsigned short* rvrow = Hb + (eAs ^ 1) * HD + kq * 4;

    // ---- Wh @ (Sb - Hbrev), depth-1 prefetch (min live regs) ----
    v4f acc[10];
    #pragma unroll
    for (int n = 0; n < 10; ++n) acc[n] = (v4f){0.f, 0.f, 0.f, 0.f};

    ushort4 ps = *(const ushort4*)(sbrow);
    ushort4 pr = *(const ushort4*)(rvrow);
    #pragma unroll
    for (int c = 0; c < 10; ++c) {
        const v4s a = mdiff(ps, pr);
        if (c < 9) {
            ps = *(const ushort4*)(sbrow + (c + 1) * KC);
            pr = *(const ushort4*)(rvrow + (c + 1) * KC);
        }
        #pragma unroll
        for (int n = 0; n < 10; ++n) {
            const v4s b = *(const v4s*)&Whl[(n * 16 + cl) * WHP + c * KC + kq * 4];
            acc[n] = __builtin_amdgcn_mfma_f32_16x16x16bf16_1k(a, b, acc[n], 0, 0, 0);
        }
    }
    // All rev-row (Hb) reads issued above; stores below are same-wave ordered.

    // ---- epilogue: per-n fused Q + Pb gather + store ----
    v4s aq;
    {
        const float* earow = ea + eAs * BD;
        if (kq < 3) {
            #pragma unroll
            for (int j = 0; j < 4; ++j) aq[j] = (short)f2b(earow[kq * 4 + j]);
        } else {
            aq[0] = (short)f2b(earow[12]);
            aq[1] = (short)f2b(earow[13]);
            aq[2] = 0; aq[3] = 0;
        }
    }
    int srcC[4];
    #pragma unroll
    for (int rr = 0; rr < 4; ++rr) {
        const long e = base + kq * 4 + rr;
        srcC[rr] = src[(e < E_EDGES) ? e : 0];
    }

    #pragma unroll
    for (int n = 0; n < 10; ++n) {
        const int col = n * 16 + cl;
        v4s bq;
        {
            const float* wr = Wi + (long)col * K1 + HD + kq * 4;
            if (kq < 3) {
                #pragma unroll
                for (int j = 0; j < 4; ++j) bq[j] = (short)f2b(wr[j]);
            } else {
                bq[0] = (short)f2b(wr[0]);
                bq[1] = (short)f2b(wr[1]);
                bq[2] = 0; bq[3] = 0;
            }
        }
        const v4f q = __builtin_amdgcn_mfma_f32_16x16x16bf16_1k(
                          aq, bq, (v4f){0.f, 0.f, 0.f, 0.f}, 0, 0, 0);
        const float bb = bh[col];
        #pragma unroll
        for (int rr = 0; rr < 4; ++rr) {
            const long e = base + kq * 4 + rr;
            if (e < E_EDGES) {
                const float pv = b2f(Pb[(long)srcC[rr] * HD + col]);
                float h0 = pv + q[rr];
                h0 = h0 > 0.f ? h0 : 0.f;
                float v = h0 + acc[n][rr] + bb;
                v = v > 0.f ? v : 0.f;
                Hb[e * HD + col] = f2b(v);
            }
        }
    }
}

// ============================ output =======================================
__global__ __launch_bounds__(256, 2)
void k_out(const float* __restrict__ x, const float* __restrict__ Mg,
           const float* __restrict__ Wo, const float* __restrict__ bo,
           float* __restrict__ out)
{
    __shared__ float At[KC][TE + 4];
    __shared__ float Wt[KC][WP];

    const int  t    = threadIdx.x;
    const long base = (long)blockIdx.x * TE;
    const int  se  = t >> 2;
    const int  skq = t & 3;
    const long gn  = base + se;
    const bool ev  = gn < N_NODES;
    const long gnc = ev ? gn : 0;
    const float* xrow = x  + gnc * HD;
    const float* mrow = Mg + gnc * HD;
    const int tr = t >> 4, tc = t & 15;

    float acc[4][10];
    #pragma unroll
    for (int i = 0; i < 4; ++i)
        #pragma unroll
        for (int j = 0; j < 10; ++j) acc[i][j] = 0.f;

    for (int c = 0; c < KO / KC; ++c) {
        const int k0 = c * KC;
        __syncthreads();
        {
            const int kb = k0 + skq * 4;
            const float4 v = (kb < HD) ? *(const float4*)(xrow + kb)
                                       : *(const float4*)(mrow + (kb - HD));
            At[skq * 4 + 0][se] = v.x;
            At[skq * 4 + 1][se] = v.y;
            At[skq * 4 + 2][se] = v.z;
            At[skq * 4 + 3][se] = v.w;
        }
        for (int i = t; i < HD * KC; i += 256) {
            const int kk = i & (KC - 1);
            const int h  = i >> 4;
            Wt[kk][h] = Wo[h * KO + k0 + kk];
        }
        __syncthreads();
        gemm_chunk(acc, At, Wt, tr, tc);
    }
    #pragma unroll
    for (int i = 0; i < 4; ++i) {
        const long n = base + tr * 4 + i;
        if (n >= N_NODES) break;
        float* op = out + n * HD + tc * 10;
        #pragma unroll
        for (int j = 0; j < 10; j += 2) {
            float v0 = acc[i][j]     + bo[tc * 10 + j];
            float v1 = acc[i][j + 1] + bo[tc * 10 + j + 1];
            v0 = v0 > 0.f ? v0 : 0.f;
            v1 = v1 > 0.f ? v1 : 0.f;
            *(float2*)(op + j) = make_float2(v0, v1);
        }
    }
}

// ---------------------------------------------------------------------------
extern "C" void kernel_launch(void* const* d_in, const int* in_sizes, int n_in,
                              void* d_out, int out_size, void* d_ws, size_t ws_size,
                              hipStream_t stream)
{
    const float* x  = (const float*)d_in[0];
    const float* ea = (const float*)d_in[1];
    const int*   ei = (const int*)d_in[2];
    const float* Wi = (const float*)d_in[4];
    const float* bi = (const float*)d_in[5];
    const float* Wh = (const float*)d_in[6];
    const float* bh = (const float*)d_in[7];
    const float* Wo = (const float*)d_in[8];
    const float* bo = (const float*)d_in[9];
    float* out = (float*)d_out;

    const int* src = ei;
    const int* dst = ei + E_EDGES;

    const int gM  = (E_EDGES + TM - 1) / TM;      // 3907
    const int gN  = (N_NODES + TE - 1) / TE;      // 782
    const int gF  = (N_NODES + 3) / 4;            // 12500
    const int gEe = (E_EDGES + 255) / 256;        // 1954

    // ws: Hb bf16 (160e6) | Mf fp32 (32e6) | CSR (~2.6e6)  -> 194.6e6 proven
    char* w = (char*)d_ws;
    unsigned short* Hb = (unsigned short*)(w);
    float* Mf  = (float*)(w + 160000000);
    int*   ptr = (int*)  (w + 192000000);
    int*   cnt = (int*)  (w + 192200016);
    int*   cur = (int*)  (w + 192400016);
    int*   eid = (int*)  (w + 192600016);
    // d_out hosts Pb (16e6) + Sb (16e6) until k_out.
    unsigned short* Pb = (unsigned short*)d_out;
    unsigned short* Sb = (unsigned short*)((char*)d_out + 16000000);

    k_zero<<<(100000 + 1023) / 1024, 256, 0, stream>>>((float*)cnt, 100000);
    k_csr_count<<<gEe, 256, 0, stream>>>(dst, cnt);
    k_csr_scan<<<1, 1024, 0, stream>>>(cnt, ptr);
    k_csr_fill<<<gEe, 256, 0, stream>>>(dst, ptr, cur, eid);

    k_nodeproj<<<gN, 256, 0, stream>>>(x, Wi, bi, Pb);
    k_h0m<<<gM, 512, 0, stream>>>(ea, src, Wi, Pb, Hb);                   // H0
    k_segb<0><<<gF, 256, 0, stream>>>(Hb, ptr, eid, x, Sb, nullptr);      // S0
    k_updm1<<<gM, 512, 0, stream>>>(Sb, src, Wh, bh, Hb);                 // H1
    k_segb<0><<<gF, 256, 0, stream>>>(Hb, ptr, eid, x, Sb, nullptr);      // S1
    k_updm2<<<gM, 512, 0, stream>>>(Sb, ea, src, Wi, Wh, bh, Pb, Hb);     // H2
    k_segb<1><<<gF, 256, 0, stream>>>(Hb, ptr, eid, x, nullptr, Mf);      // M
    k_out<<<gN, 256, 0, stream>>>(x, Mf, Wo, bo, out);
}

// Round 6
// 1047.689 us; speedup vs baseline: 1.5075x; 1.0480x over previous
//
#include <hip/hip_runtime.h>

// Chemprop BondMessagePassing, DEPTH=3, eval mode.
// R13: consolidation round (R5 post-mortem: (512,6) cap-85 regime slower than
//   R3's (512,4) no-spill 16-wave regime; depth-1 prefetch cut memory ILP).
//  - k_updm2: (512,4) + depth-2 prefetch + deferred-h0 epilogue + Wieb table.
//  - Wieb: bf16 [col][16] copy of Wi_e (5 KB) in ws slack, filled by
//    k_nodeproj block 0; Q-phase B-frag = one ushort4 load (was 4 f32 loads
//    + converts per n). Used by h0m and updm2.
//  - k_segb: 4x unrolled CSR gather (4 row streams, 12 accumulators).
//  - k_out: (256,3) -- grid 782 = 3.05 blocks/CU, was capped at 2.
//  - k_updm1 byte-identical to R11/R12.
// ws: Hb bf16 @0 (160e6) | Mf fp32 @160e6 (32e6) | CSR @192e6 | Wieb @194600064.
// d_out hosts Pb(16e6)+Sb(16e6) until k_out.

#define E_EDGES 500000
#define N_NODES 50000
#define HD      160
#define BD      14
#define K1      174
#define KO      320

#define TE 64
#define KC 16
#define NC2 (HD / KC)   // 10
#define WP  (HD + 8)    // Wt stride (vector kernels)

#define TM   128        // edges per MFMA block (8 waves x 16)
#define WHP  164        // Whl padded k-stride (shorts)

typedef __attribute__((ext_vector_type(4))) short v4s;
typedef __attribute__((ext_vector_type(4))) float v4f;

// ---- bf16 helpers (RNE) ----
__device__ __forceinline__ unsigned short f2b(float v) {
    unsigned u = __float_as_uint(v);
    u += 0x7FFFu + ((u >> 16) & 1u);
    return (unsigned short)(u >> 16);
}
__device__ __forceinline__ float b2f(unsigned short h) {
    return __uint_as_float(((unsigned)h) << 16);
}

__device__ __forceinline__ v4s mdiff(ushort4 s, ushort4 r) {
    v4s a;
    a[0] = (short)f2b(b2f(s.x) - b2f(r.x));
    a[1] = (short)f2b(b2f(s.y) - b2f(r.y));
    a[2] = (short)f2b(b2f(s.z) - b2f(r.z));
    a[3] = (short)f2b(b2f(s.w) - b2f(r.w));
    return a;
}

// ---------------------------------------------------------------------------
__global__ void k_zero(float* __restrict__ p, long n)
{
    const long i = (long)blockIdx.x * 1024 + (long)threadIdx.x * 4;
    if (i + 3 < n) *(float4*)(p + i) = make_float4(0.f, 0.f, 0.f, 0.f);
}

// ---------------------------------------------------------------------------
__device__ __forceinline__
void gemm_chunk(float acc[4][10], const float At[KC][TE + 4],
                const float Wt[KC][WP], int tr, int tc)
{
    #pragma unroll
    for (int k = 0; k < KC; ++k) {
        const float4 a  = *(const float4*)&At[k][tr * 4];
        const float* wp = &Wt[k][tc * 10];
        float w[10];
        #pragma unroll
        for (int j = 0; j < 10; j += 2) {
            const float2 w2 = *(const float2*)(wp + j);
            w[j] = w2.x; w[j + 1] = w2.y;
        }
        #pragma unroll
        for (int j = 0; j < 10; ++j) {
            acc[0][j] = fmaf(a.x, w[j], acc[0][j]);
            acc[1][j] = fmaf(a.y, w[j], acc[1][j]);
            acc[2][j] = fmaf(a.z, w[j], acc[2][j]);
            acc[3][j] = fmaf(a.w, w[j], acc[3][j]);
        }
    }
}

// ============================ CSR build ====================================
__global__ void k_csr_count(const int* __restrict__ dst, int* __restrict__ cnt)
{
    const int e = blockIdx.x * 256 + threadIdx.x;
    if (e < E_EDGES) atomicAdd(&cnt[dst[e]], 1);
}

#define BPT 49
__global__ __launch_bounds__(1024)
void k_csr_scan(const int* __restrict__ cnt, int* __restrict__ ptr)
{
    __shared__ int part[1024];
    const int t  = threadIdx.x;
    const int lo = t * BPT;
    const int hi = min(lo + BPT, N_NODES);
    int s = 0;
    for (int i = lo; i < hi; ++i) s += cnt[i];
    part[t] = s;
    __syncthreads();
    for (int off = 1; off < 1024; off <<= 1) {
        int v = 0;
        if (t >= off) v = part[t - off];
        __syncthreads();
        if (t >= off) part[t] += v;
        __syncthreads();
    }
    int run = (t == 0) ? 0 : part[t - 1];
    for (int i = lo; i < hi; ++i) { ptr[i] = run; run += cnt[i]; }
    if (t == 1023) ptr[N_NODES] = part[1023];
}

__global__ void k_csr_fill(const int* __restrict__ dst, const int* __restrict__ ptr,
                           int* __restrict__ cur, int* __restrict__ eid)
{
    const int e = blockIdx.x * 256 + threadIdx.x;
    if (e < E_EDGES) {
        const int d   = dst[e];
        const int pos = atomicAdd(&cur[d], 1);
        eid[ptr[d] + pos] = e;
    }
}

// ============================ node projection ==============================
// Pb[n] = bf16(Wi_x @ x[n] + bi)  (NO relu). Block 0 also fills the Wieb
// table: Wieb[col*16 + k'] = bf16(Wi[col][HD+k']) for k'<14, else 0.
__global__ __launch_bounds__(256, 2)
void k_nodeproj(const float* __restrict__ x, const float* __restrict__ Wi,
                const float* __restrict__ bi, unsigned short* __restrict__ Pb,
                unsigned short* __restrict__ Wieb)
{
    __shared__ float At[KC][TE + 4];
    __shared__ float Wt[KC][WP];

    const int  t    = threadIdx.x;
    const long base = (long)blockIdx.x * TE;
    const int  se  = t >> 2;
    const int  skq = t & 3;
    const long gn  = base + se;
    const long gnc = (gn < N_NODES) ? gn : 0;
    const float* xrow = x + gnc * HD;
    const int tr = t >> 4, tc = t & 15;

    if (blockIdx.x == 0 && t < HD) {
        const float* wr = Wi + (long)t * K1 + HD;
        unsigned short* wo = Wieb + t * 16;
        #pragma unroll
        for (int k = 0; k < 16; ++k) wo[k] = (k < BD) ? f2b(wr[k]) : (unsigned short)0;
    }

    float acc[4][10];
    #pragma unroll
    for (int i = 0; i < 4; ++i)
        #pragma unroll
        for (int j = 0; j < 10; ++j) acc[i][j] = 0.f;

    for (int c = 0; c < NC2; ++c) {
        const int k0 = c * KC;
        __syncthreads();
        {
            const float4 v = *(const float4*)(xrow + k0 + skq * 4);
            At[skq * 4 + 0][se] = v.x;
            At[skq * 4 + 1][se] = v.y;
            At[skq * 4 + 2][se] = v.z;
            At[skq * 4 + 3][se] = v.w;
        }
        for (int i = t; i < HD * KC; i += 256) {
            const int kk = i & (KC - 1);
            const int h  = i >> 4;
            Wt[kk][h] = Wi[h * K1 + k0 + kk];
        }
        __syncthreads();
        gemm_chunk(acc, At, Wt, tr, tc);
    }
    #pragma unroll
    for (int i = 0; i < 4; ++i) {
        const long n = base + tr * 4 + i;
        if (n >= N_NODES) break;
        unsigned short* pp = Pb + n * HD + tc * 10;
        #pragma unroll
        for (int j = 0; j < 10; j += 2) {
            const float v0 = acc[i][j]     + bi[tc * 10 + j];
            const float v1 = acc[i][j + 1] + bi[tc * 10 + j + 1];
            *(ushort2*)(pp + j) = make_ushort2(f2b(v0), f2b(v1));
        }
    }
}

// ============================ H0 (MFMA, no LDS) ============================
// Hb[e] = bf16(relu(Pb[src[e]] + ea[e] @ Wi_e^T)), 16 edges/wave.
__global__ __launch_bounds__(512, 6)
void k_h0m(const float* __restrict__ ea, const int* __restrict__ src,
           const unsigned short* __restrict__ Wieb,
           const unsigned short* __restrict__ Pb,
           unsigned short* __restrict__ Hb)
{
    const int  t    = threadIdx.x;
    const int  w    = t >> 6;
    const int  lane = t & 63;
    const int  cl   = lane & 15;
    const int  kq   = lane >> 4;
    const long base = (long)blockIdx.x * TM + w * 16;

    const long eA  = base + cl;
    const long eAs = (eA < E_EDGES) ? eA : 0;

    // A-frag from ea row (k' = kq*4+j; guard k' < BD without OOB reads)
    v4s aq;
    {
        const float* earow = ea + eAs * BD;
        if (kq < 3) {
            #pragma unroll
            for (int j = 0; j < 4; ++j) aq[j] = (short)f2b(earow[kq * 4 + j]);
        } else {
            aq[0] = (short)f2b(earow[12]);
            aq[1] = (short)f2b(earow[13]);
            aq[2] = 0; aq[3] = 0;
        }
    }
    int srcC[4];
    #pragma unroll
    for (int rr = 0; rr < 4; ++rr) {
        const long e = base + kq * 4 + rr;
        srcC[rr] = src[(e < E_EDGES) ? e : 0];
    }

    #pragma unroll
    for (int n = 0; n < 10; ++n) {
        const int col = n * 16 + cl;
        const v4s bq = *(const v4s*)&Wieb[col * 16 + kq * 4];
        const v4f q = __builtin_amdgcn_mfma_f32_16x16x16bf16_1k(
                          aq, bq, (v4f){0.f, 0.f, 0.f, 0.f}, 0, 0, 0);
        #pragma unroll
        for (int rr = 0; rr < 4; ++rr) {
            const long e = base + kq * 4 + rr;
            if (e < E_EDGES) {
                const float pv = b2f(Pb[(long)srcC[rr] * HD + col]);
                float v = pv + q[rr];
                v = v > 0.f ? v : 0.f;
                Hb[e * HD + col] = f2b(v);
            }
        }
    }
}

// ============================ segment sum ==================================
// FINAL=0: write bf16 Sb. FINAL=1: write fp32 S with sum==0 -> x fallback.
// 4x unrolled edge loop (4 row streams, 12 accumulators -> 4x memory ILP).
template <int FINAL>
__global__ void k_segb(const unsigned short* __restrict__ Hb,
                       const int* __restrict__ ptr, const int* __restrict__ eid,
                       const float* __restrict__ x,
                       unsigned short* __restrict__ Sb, float* __restrict__ S)
{
    const int  lane = threadIdx.x & 63;
    const int  w    = threadIdx.x >> 6;
    const long n    = (long)blockIdx.x * 4 + w;
    if (n >= N_NODES) return;
    const int p0 = ptr[n], p1 = ptr[n + 1];
    float a0 = 0.f, a1 = 0.f, a2 = 0.f;
    float b0 = 0.f, b1 = 0.f, b2 = 0.f;
    float c0 = 0.f, c1 = 0.f, c2 = 0.f;
    float d0 = 0.f, d1 = 0.f, d2 = 0.f;
    int i = p0;
    for (; i + 4 <= p1; i += 4) {
        const int e0 = eid[i], e1 = eid[i + 1], e2 = eid[i + 2], e3 = eid[i + 3];
        const unsigned short* r0 = Hb + (long)e0 * HD;
        const unsigned short* r1 = Hb + (long)e1 * HD;
        const unsigned short* r2 = Hb + (long)e2 * HD;
        const unsigned short* r3 = Hb + (long)e3 * HD;
        a0 += b2f(r0[lane]);
        b0 += b2f(r1[lane]);
        c0 += b2f(r2[lane]);
        d0 += b2f(r3[lane]);
        a1 += b2f(r0[64 + lane]);
        b1 += b2f(r1[64 + lane]);
        c1 += b2f(r2[64 + lane]);
        d1 += b2f(r3[64 + lane]);
        if (lane < 32) {
            a2 += b2f(r0[128 + lane]);
            b2 += b2f(r1[128 + lane]);
            c2 += b2f(r2[128 + lane]);
            d2 += b2f(r3[128 + lane]);
        }
    }
    for (; i < p1; ++i) {
        const unsigned short* r0 = Hb + (long)eid[i] * HD;
        a0 += b2f(r0[lane]);
        a1 += b2f(r0[64 + lane]);
        if (lane < 32) a2 += b2f(r0[128 + lane]);
    }
    a0 += b0 + c0 + d0;
    a1 += b1 + c1 + d1;
    a2 += b2 + c2 + d2;

    const long sb = n * HD;
    if (FINAL) {
        float s = a0 + a1 + a2;
        #pragma unroll
        for (int off = 32; off > 0; off >>= 1) s += __shfl_xor(s, off, 64);
        if (s == 0.f) {
            S[sb + lane]      = x[sb + lane];
            S[sb + 64 + lane] = x[sb + 64 + lane];
            if (lane < 32) S[sb + 128 + lane] = x[sb + 128 + lane];
            return;
        }
        S[sb + lane]      = a0;
        S[sb + 64 + lane] = a1;
        if (lane < 32) S[sb + 128 + lane] = a2;
    } else {
        Sb[sb + lane]      = f2b(a0);
        Sb[sb + 64 + lane] = f2b(a1);
        if (lane < 32) Sb[sb + 128 + lane] = f2b(a2);
    }
}

// ============================ MFMA update, iter 1 ==========================
// Hb[e] = bf16(relu(Hb[e] + Wh @ (Sb[src[e]] - Hb[e^1]) + bh))
// (Hb still holds H0 = h0.)  8 waves x 16 edges; no barriers after staging.
__global__ __launch_bounds__(512, 6)
void k_updm1(const unsigned short* __restrict__ Sb,
             const int* __restrict__ src,
             const float* __restrict__ Wh, const float* __restrict__ bh,
             unsigned short* __restrict__ Hb)
{
    __shared__ unsigned short Whl[HD * WHP];   // 52480 B, [h][k] bf16

    const int t = threadIdx.x;
    for (int i = t * 4; i < HD * HD; i += 2048) {
        const int h = i / HD, k = i % HD;
        const float4 wv = *(const float4*)(Wh + h * HD + k);
        *(ushort4*)&Whl[h * WHP + k] =
            make_ushort4(f2b(wv.x), f2b(wv.y), f2b(wv.z), f2b(wv.w));
    }
    __syncthreads();

    const int  w    = t >> 6;
    const int  lane = t & 63;
    const int  cl   = lane & 15;     // A-row / B-col / C-col selector
    const int  kq   = lane >> 4;     // k-group 0..3
    const long base = (long)blockIdx.x * TM + w * 16;

    const long eA  = base + cl;
    const long eAs = (eA < E_EDGES) ? eA : 0;
    const int  sA  = src[eAs];
    const unsigned short* sbrow = Sb + (long)sA * HD + kq * 4;
    const unsigned short* rvrow = Hb + (eAs ^ 1) * HD + kq * 4;

    v4f acc[10];
    #pragma unroll
    for (int n = 0; n < 10; ++n) acc[n] = (v4f){0.f, 0.f, 0.f, 0.f};

    // depth-2 prefetch of the gather streams
    ushort4 ps0 = *(const ushort4*)(sbrow);
    ushort4 pr0 = *(const ushort4*)(rvrow);
    ushort4 ps1 = *(const ushort4*)(sbrow + KC);
    ushort4 pr1 = *(const ushort4*)(rvrow + KC);
    #pragma unroll
    for (int c = 0; c < 10; ++c) {
        const v4s a = mdiff(ps0, pr0);
        ps0 = ps1; pr0 = pr1;
        if (c + 2 < 10) {
            ps1 = *(const ushort4*)(sbrow + (c + 2) * KC);
            pr1 = *(const ushort4*)(rvrow + (c + 2) * KC);
        }
        #pragma unroll
        for (int n = 0; n < 10; ++n) {
            const v4s b = *(const v4s*)&Whl[(n * 16 + cl) * WHP + c * KC + kq * 4];
            acc[n] = __builtin_amdgcn_mfma_f32_16x16x16bf16_1k(a, b, acc[n], 0, 0, 0);
        }
    }

    #pragma unroll
    for (int n = 0; n < 10; ++n) {
        const int col = n * 16 + cl;
        const float bb = bh[col];
        #pragma unroll
        for (int rr = 0; rr < 4; ++rr) {
            const long e = base + kq * 4 + rr;
            if (e < E_EDGES) {
                unsigned short* hp = Hb + e * HD + col;
                float v = b2f(*hp) + acc[n][rr] + bb;
                v = v > 0.f ? v : 0.f;
                *hp = f2b(v);
            }
        }
    }
}

// ============================ MFMA update, iter 2 ==========================
// DEFERRED-h0: Wh K-loop first (acc in AGPR, depth-2 prefetch), then per-n
// epilogue: q = ea @ Wi_e^T (MFMA, B-frag from Wieb table) + Pb gather +
// fused relu/store.  (512,4): R3-proven no-spill regime.
__global__ __launch_bounds__(512, 4)
void k_updm2(const unsigned short* __restrict__ Sb,
             const float* __restrict__ ea, const int* __restrict__ src,
             const unsigned short* __restrict__ Wieb,
             const float* __restrict__ Wh, const float* __restrict__ bh,
             const unsigned short* __restrict__ Pb,
             unsigned short* __restrict__ Hb)
{
    __shared__ unsigned short Whl[HD * WHP];    // 52480 B

    const int t = threadIdx.x;
    for (int i = t * 4; i < HD * HD; i += 2048) {
        const int h = i / HD, k = i % HD;
        const float4 wv = *(const float4*)(Wh + h * HD + k);
        *(ushort4*)&Whl[h * WHP + k] =
            make_ushort4(f2b(wv.x), f2b(wv.y), f2b(wv.z), f2b(wv.w));
    }
    __syncthreads();

    const int  w    = t >> 6;
    const int  lane = t & 63;
    const int  cl   = lane & 15;
    const int  kq   = lane >> 4;
    const long base = (long)blockIdx.x * TM + w * 16;

    const long eA  = base + cl;
    const long eAs = (eA < E_EDGES) ? eA : 0;
    const int  sA  = src[eAs];
    const unsigned short* sbrow = Sb + (long)sA * HD + kq * 4;
    const unsigned short* rvrow = Hb + (eAs ^ 1) * HD + kq * 4;

    // ---- Wh @ (Sb - Hbrev), depth-2 prefetch ----
    v4f acc[10];
    #pragma unroll
    for (int n = 0; n < 10; ++n) acc[n] = (v4f){0.f, 0.f, 0.f, 0.f};

    ushort4 ps0 = *(const ushort4*)(sbrow);
    ushort4 pr0 = *(const ushort4*)(rvrow);
    ushort4 ps1 = *(const ushort4*)(sbrow + KC);
    ushort4 pr1 = *(const ushort4*)(rvrow + KC);
    #pragma unroll
    for (int c = 0; c < 10; ++c) {
        const v4s a = mdiff(ps0, pr0);
        ps0 = ps1; pr0 = pr1;
        if (c + 2 < 10) {
            ps1 = *(const ushort4*)(sbrow + (c + 2) * KC);
            pr1 = *(const ushort4*)(rvrow + (c + 2) * KC);
        }
        #pragma unroll
        for (int n = 0; n < 10; ++n) {
            const v4s b = *(const v4s*)&Whl[(n * 16 + cl) * WHP + c * KC + kq * 4];
            acc[n] = __builtin_amdgcn_mfma_f32_16x16x16bf16_1k(a, b, acc[n], 0, 0, 0);
        }
    }
    // All rev-row (Hb) reads issued above; stores below are same-wave ordered.

    // ---- epilogue: per-n fused Q + Pb gather + store ----
    v4s aq;
    {
        const float* earow = ea + eAs * BD;
        if (kq < 3) {
            #pragma unroll
            for (int j = 0; j < 4; ++j) aq[j] = (short)f2b(earow[kq * 4 + j]);
        } else {
            aq[0] = (short)f2b(earow[12]);
            aq[1] = (short)f2b(earow[13]);
            aq[2] = 0; aq[3] = 0;
        }
    }
    int srcC[4];
    #pragma unroll
    for (int rr = 0; rr < 4; ++rr) {
        const long e = base + kq * 4 + rr;
        srcC[rr] = src[(e < E_EDGES) ? e : 0];
    }

    #pragma unroll
    for (int n = 0; n < 10; ++n) {
        const int col = n * 16 + cl;
        const v4s bq = *(const v4s*)&Wieb[col * 16 + kq * 4];
        const v4f q = __builtin_amdgcn_mfma_f32_16x16x16bf16_1k(
                          aq, bq, (v4f){0.f, 0.f, 0.f, 0.f}, 0, 0, 0);
        const float bb = bh[col];
        #pragma unroll
        for (int rr = 0; rr < 4; ++rr) {
            const long e = base + kq * 4 + rr;
            if (e < E_EDGES) {
                const float pv = b2f(Pb[(long)srcC[rr] * HD + col]);
                float h0 = pv + q[rr];
                h0 = h0 > 0.f ? h0 : 0.f;
                float v = h0 + acc[n][rr] + bb;
                v = v > 0.f ? v : 0.f;
                Hb[e * HD + col] = f2b(v);
            }
        }
    }
}

// ============================ output =======================================
__global__ __launch_bounds__(256, 3)
void k_out(const float* __restrict__ x, const float* __restrict__ Mg,
           const float* __restrict__ Wo, const float* __restrict__ bo,
           float* __restrict__ out)
{
    __shared__ float At[KC][TE + 4];
    __shared__ float Wt[KC][WP];

    const int  t    = threadIdx.x;
    const long base = (long)blockIdx.x * TE;
    const int  se  = t >> 2;
    const int  skq = t & 3;
    const long gn  = base + se;
    const bool ev  = gn < N_NODES;
    const long gnc = ev ? gn : 0;
    const float* xrow = x  + gnc * HD;
    const float* mrow = Mg + gnc * HD;
    const int tr = t >> 4, tc = t & 15;

    float acc[4][10];
    #pragma unroll
    for (int i = 0; i < 4; ++i)
        #pragma unroll
        for (int j = 0; j < 10; ++j) acc[i][j] = 0.f;

    for (int c = 0; c < KO / KC; ++c) {
        const int k0 = c * KC;
        __syncthreads();
        {
            const int kb = k0 + skq * 4;
            const float4 v = (kb < HD) ? *(const float4*)(xrow + kb)
                                       : *(const float4*)(mrow + (kb - HD));
            At[skq * 4 + 0][se] = v.x;
            At[skq * 4 + 1][se] = v.y;
            At[skq * 4 + 2][se] = v.z;
            At[skq * 4 + 3][se] = v.w;
        }
        for (int i = t; i < HD * KC; i += 256) {
            const int kk = i & (KC - 1);
            const int h  = i >> 4;
            Wt[kk][h] = Wo[h * KO + k0 + kk];
        }
        __syncthreads();
        gemm_chunk(acc, At, Wt, tr, tc);
    }
    #pragma unroll
    for (int i = 0; i < 4; ++i) {
        const long n = base + tr * 4 + i;
        if (n >= N_NODES) break;
        float* op = out + n * HD + tc * 10;
        #pragma unroll
        for (int j = 0; j < 10; j += 2) {
            float v0 = acc[i][j]     + bo[tc * 10 + j];
            float v1 = acc[i][j + 1] + bo[tc * 10 + j + 1];
            v0 = v0 > 0.f ? v0 : 0.f;
            v1 = v1 > 0.f ? v1 : 0.f;
            *(float2*)(op + j) = make_float2(v0, v1);
        }
    }
}

// ---------------------------------------------------------------------------
extern "C" void kernel_launch(void* const* d_in, const int* in_sizes, int n_in,
                              void* d_out, int out_size, void* d_ws, size_t ws_size,
                              hipStream_t stream)
{
    const float* x  = (const float*)d_in[0];
    const float* ea = (const float*)d_in[1];
    const int*   ei = (const int*)d_in[2];
    const float* Wi = (const float*)d_in[4];
    const float* bi = (const float*)d_in[5];
    const float* Wh = (const float*)d_in[6];
    const float* bh = (const float*)d_in[7];
    const float* Wo = (const float*)d_in[8];
    const float* bo = (const float*)d_in[9];
    float* out = (float*)d_out;

    const int* src = ei;
    const int* dst = ei + E_EDGES;

    const int gM  = (E_EDGES + TM - 1) / TM;      // 3907
    const int gN  = (N_NODES + TE - 1) / TE;      // 782
    const int gF  = (N_NODES + 3) / 4;            // 12500
    const int gEe = (E_EDGES + 255) / 256;        // 1954

    // ws: Hb bf16 (160e6) | Mf fp32 (32e6) | CSR (~2.6e6) | Wieb (5 KB)
    char* w = (char*)d_ws;
    unsigned short* Hb  = (unsigned short*)(w);
    float* Mf   = (float*)(w + 160000000);
    int*   ptr  = (int*)  (w + 192000000);
    int*   cnt  = (int*)  (w + 192200016);
    int*   cur  = (int*)  (w + 192400016);
    int*   eid  = (int*)  (w + 192600016);
    unsigned short* Wieb = (unsigned short*)(w + 194600064);
    // d_out hosts Pb (16e6) + Sb (16e6) until k_out.
    unsigned short* Pb = (unsigned short*)d_out;
    unsigned short* Sb = (unsigned short*)((char*)d_out + 16000000);

    k_zero<<<(100000 + 1023) / 1024, 256, 0, stream>>>((float*)cnt, 100000);
    k_csr_count<<<gEe, 256, 0, stream>>>(dst, cnt);
    k_csr_scan<<<1, 1024, 0, stream>>>(cnt, ptr);
    k_csr_fill<<<gEe, 256, 0, stream>>>(dst, ptr, cur, eid);

    k_nodeproj<<<gN, 256, 0, stream>>>(x, Wi, bi, Pb, Wieb);
    k_h0m<<<gM, 512, 0, stream>>>(ea, src, Wieb, Pb, Hb);                 // H0
    k_segb<0><<<gF, 256, 0, stream>>>(Hb, ptr, eid, x, Sb, nullptr);      // S0
    k_updm1<<<gM, 512, 0, stream>>>(Sb, src, Wh, bh, Hb);                 // H1
    k_segb<0><<<gF, 256, 0, stream>>>(Hb, ptr, eid, x, Sb, nullptr);      // S1
    k_updm2<<<gM, 512, 0, stream>>>(Sb, ea, src, Wieb, Wh, bh, Pb, Hb);   // H2
    k_segb<1><<<gF, 256, 0, stream>>>(Hb, ptr, eid, x, nullptr, Mf);      // M
    k_out<<<gN, 256, 0, stream>>>(x, Mf, Wo, bo, out);
}

// Round 7
// 976.089 us; speedup vs baseline: 1.6181x; 1.0734x over previous
//
#include <hip/hip_runtime.h>

// Chemprop BondMessagePassing, DEPTH=3, eval mode.
// R14: latency-depth round (R6 post-mortem: K-loop depth-2 prefetch = ~220cy
//   cover vs ~900cy HBM-cold rev-row latency -> stall-bound at 2.2 TB/s).
//  - k_updm1/k_updm2: FULL 10-deep prefetch (20 ushort4 = 40 VGPR) of the
//    Sb/Hbrev streams; compiler emits incremental vmcnt waits. (512,4) both:
//    ~70 arch + 40 AGPR = ~110 regs, no spill, ~18 waves/CU.
//  - k_updm2 epilogue: (bq, 4xPb) software-pipelined one n ahead.
//  - k_h0m: all 40 Pb loads + 10 Wieb frags issued upfront, then MFMA loop.
//  - k_segb: 4x main + 2x mid + 1x tail (avg degree 10).
// ws: Hb bf16 @0 (160e6) | Mf fp32 @160e6 (32e6) | CSR @192e6 | Wieb @194600064.
// d_out hosts Pb(16e6)+Sb(16e6) until k_out.

#define E_EDGES 500000
#define N_NODES 50000
#define HD      160
#define BD      14
#define K1      174
#define KO      320

#define TE 64
#define KC 16
#define NC2 (HD / KC)   // 10
#define WP  (HD + 8)    // Wt stride (vector kernels)

#define TM   128        // edges per MFMA block (8 waves x 16)
#define WHP  164        // Whl padded k-stride (shorts)

typedef __attribute__((ext_vector_type(4))) short v4s;
typedef __attribute__((ext_vector_type(4))) float v4f;

// ---- bf16 helpers (RNE) ----
__device__ __forceinline__ unsigned short f2b(float v) {
    unsigned u = __float_as_uint(v);
    u += 0x7FFFu + ((u >> 16) & 1u);
    return (unsigned short)(u >> 16);
}
__device__ __forceinline__ float b2f(unsigned short h) {
    return __uint_as_float(((unsigned)h) << 16);
}

__device__ __forceinline__ v4s mdiff(ushort4 s, ushort4 r) {
    v4s a;
    a[0] = (short)f2b(b2f(s.x) - b2f(r.x));
    a[1] = (short)f2b(b2f(s.y) - b2f(r.y));
    a[2] = (short)f2b(b2f(s.z) - b2f(r.z));
    a[3] = (short)f2b(b2f(s.w) - b2f(r.w));
    return a;
}

// ---------------------------------------------------------------------------
__global__ void k_zero(float* __restrict__ p, long n)
{
    const long i = (long)blockIdx.x * 1024 + (long)threadIdx.x * 4;
    if (i + 3 < n) *(float4*)(p + i) = make_float4(0.f, 0.f, 0.f, 0.f);
}

// ---------------------------------------------------------------------------
__device__ __forceinline__
void gemm_chunk(float acc[4][10], const float At[KC][TE + 4],
                const float Wt[KC][WP], int tr, int tc)
{
    #pragma unroll
    for (int k = 0; k < KC; ++k) {
        const float4 a  = *(const float4*)&At[k][tr * 4];
        const float* wp = &Wt[k][tc * 10];
        float w[10];
        #pragma unroll
        for (int j = 0; j < 10; j += 2) {
            const float2 w2 = *(const float2*)(wp + j);
            w[j] = w2.x; w[j + 1] = w2.y;
        }
        #pragma unroll
        for (int j = 0; j < 10; ++j) {
            acc[0][j] = fmaf(a.x, w[j], acc[0][j]);
            acc[1][j] = fmaf(a.y, w[j], acc[1][j]);
            acc[2][j] = fmaf(a.z, w[j], acc[2][j]);
            acc[3][j] = fmaf(a.w, w[j], acc[3][j]);
        }
    }
}

// ============================ CSR build ====================================
__global__ void k_csr_count(const int* __restrict__ dst, int* __restrict__ cnt)
{
    const int e = blockIdx.x * 256 + threadIdx.x;
    if (e < E_EDGES) atomicAdd(&cnt[dst[e]], 1);
}

#define BPT 49
__global__ __launch_bounds__(1024)
void k_csr_scan(const int* __restrict__ cnt, int* __restrict__ ptr)
{
    __shared__ int part[1024];
    const int t  = threadIdx.x;
    const int lo = t * BPT;
    const int hi = min(lo + BPT, N_NODES);
    int s = 0;
    for (int i = lo; i < hi; ++i) s += cnt[i];
    part[t] = s;
    __syncthreads();
    for (int off = 1; off < 1024; off <<= 1) {
        int v = 0;
        if (t >= off) v = part[t - off];
        __syncthreads();
        if (t >= off) part[t] += v;
        __syncthreads();
    }
    int run = (t == 0) ? 0 : part[t - 1];
    for (int i = lo; i < hi; ++i) { ptr[i] = run; run += cnt[i]; }
    if (t == 1023) ptr[N_NODES] = part[1023];
}

__global__ void k_csr_fill(const int* __restrict__ dst, const int* __restrict__ ptr,
                           int* __restrict__ cur, int* __restrict__ eid)
{
    const int e = blockIdx.x * 256 + threadIdx.x;
    if (e < E_EDGES) {
        const int d   = dst[e];
        const int pos = atomicAdd(&cur[d], 1);
        eid[ptr[d] + pos] = e;
    }
}

// ============================ node projection ==============================
// Pb[n] = bf16(Wi_x @ x[n] + bi)  (NO relu). Block 0 also fills the Wieb
// table: Wieb[col*16 + k'] = bf16(Wi[col][HD+k']) for k'<14, else 0.
__global__ __launch_bounds__(256, 2)
void k_nodeproj(const float* __restrict__ x, const float* __restrict__ Wi,
                const float* __restrict__ bi, unsigned short* __restrict__ Pb,
                unsigned short* __restrict__ Wieb)
{
    __shared__ float At[KC][TE + 4];
    __shared__ float Wt[KC][WP];

    const int  t    = threadIdx.x;
    const long base = (long)blockIdx.x * TE;
    const int  se  = t >> 2;
    const int  skq = t & 3;
    const long gn  = base + se;
    const long gnc = (gn < N_NODES) ? gn : 0;
    const float* xrow = x + gnc * HD;
    const int tr = t >> 4, tc = t & 15;

    if (blockIdx.x == 0 && t < HD) {
        const float* wr = Wi + (long)t * K1 + HD;
        unsigned short* wo = Wieb + t * 16;
        #pragma unroll
        for (int k = 0; k < 16; ++k) wo[k] = (k < BD) ? f2b(wr[k]) : (unsigned short)0;
    }

    float acc[4][10];
    #pragma unroll
    for (int i = 0; i < 4; ++i)
        #pragma unroll
        for (int j = 0; j < 10; ++j) acc[i][j] = 0.f;

    for (int c = 0; c < NC2; ++c) {
        const int k0 = c * KC;
        __syncthreads();
        {
            const float4 v = *(const float4*)(xrow + k0 + skq * 4);
            At[skq * 4 + 0][se] = v.x;
            At[skq * 4 + 1][se] = v.y;
            At[skq * 4 + 2][se] = v.z;
            At[skq * 4 + 3][se] = v.w;
        }
        for (int i = t; i < HD * KC; i += 256) {
            const int kk = i & (KC - 1);
            const int h  = i >> 4;
            Wt[kk][h] = Wi[h * K1 + k0 + kk];
        }
        __syncthreads();
        gemm_chunk(acc, At, Wt, tr, tc);
    }
    #pragma unroll
    for (int i = 0; i < 4; ++i) {
        const long n = base + tr * 4 + i;
        if (n >= N_NODES) break;
        unsigned short* pp = Pb + n * HD + tc * 10;
        #pragma unroll
        for (int j = 0; j < 10; j += 2) {
            const float v0 = acc[i][j]     + bi[tc * 10 + j];
            const float v1 = acc[i][j + 1] + bi[tc * 10 + j + 1];
            *(ushort2*)(pp + j) = make_ushort2(f2b(v0), f2b(v1));
        }
    }
}

// ============================ H0 (MFMA, no LDS) ============================
// Hb[e] = bf16(relu(Pb[src[e]] + ea[e] @ Wi_e^T)), 16 edges/wave.
// All Pb gathers + Wieb frags issued upfront (latency depth ~50 loads).
__global__ __launch_bounds__(512, 4)
void k_h0m(const float* __restrict__ ea, const int* __restrict__ src,
           const unsigned short* __restrict__ Wieb,
           const unsigned short* __restrict__ Pb,
           unsigned short* __restrict__ Hb)
{
    const int  t    = threadIdx.x;
    const int  w    = t >> 6;
    const int  lane = t & 63;
    const int  cl   = lane & 15;
    const int  kq   = lane >> 4;
    const long base = (long)blockIdx.x * TM + w * 16;

    const long eA  = base + cl;
    const long eAs = (eA < E_EDGES) ? eA : 0;

    // A-frag from ea row (k' = kq*4+j; guard k' < BD without OOB reads)
    v4s aq;
    {
        const float* earow = ea + eAs * BD;
        if (kq < 3) {
            #pragma unroll
            for (int j = 0; j < 4; ++j) aq[j] = (short)f2b(earow[kq * 4 + j]);
        } else {
            aq[0] = (short)f2b(earow[12]);
            aq[1] = (short)f2b(earow[13]);
            aq[2] = 0; aq[3] = 0;
        }
    }
    int srcC[4];
    #pragma unroll
    for (int rr = 0; rr < 4; ++rr) {
        const long e = base + kq * 4 + rr;
        srcC[rr] = src[(e < E_EDGES) ? e : 0];
    }

    // issue ALL gathers + table loads upfront
    unsigned short pvv[10][4];
    v4s bqa[10];
    #pragma unroll
    for (int n = 0; n < 10; ++n) {
        const int col = n * 16 + cl;
        bqa[n] = *(const v4s*)&Wieb[col * 16 + kq * 4];
        #pragma unroll
        for (int rr = 0; rr < 4; ++rr)
            pvv[n][rr] = Pb[(long)srcC[rr] * HD + col];
    }

    #pragma unroll
    for (int n = 0; n < 10; ++n) {
        const int col = n * 16 + cl;
        const v4f q = __builtin_amdgcn_mfma_f32_16x16x16bf16_1k(
                          aq, bqa[n], (v4f){0.f, 0.f, 0.f, 0.f}, 0, 0, 0);
        #pragma unroll
        for (int rr = 0; rr < 4; ++rr) {
            const long e = base + kq * 4 + rr;
            if (e < E_EDGES) {
                float v = b2f(pvv[n][rr]) + q[rr];
                v = v > 0.f ? v : 0.f;
                Hb[e * HD + col] = f2b(v);
            }
        }
    }
}

// ============================ segment sum ==================================
// FINAL=0: write bf16 Sb. FINAL=1: write fp32 S with sum==0 -> x fallback.
// 4x main + 2x mid + 1x tail (avg degree 10).
template <int FINAL>
__global__ void k_segb(const unsigned short* __restrict__ Hb,
                       const int* __restrict__ ptr, const int* __restrict__ eid,
                       const float* __restrict__ x,
                       unsigned short* __restrict__ Sb, float* __restrict__ S)
{
    const int  lane = threadIdx.x & 63;
    const int  w    = threadIdx.x >> 6;
    const long n    = (long)blockIdx.x * 4 + w;
    if (n >= N_NODES) return;
    const int p0 = ptr[n], p1 = ptr[n + 1];
    float a0 = 0.f, a1 = 0.f, a2 = 0.f;
    float b0 = 0.f, b1 = 0.f, b2 = 0.f;
    float c0 = 0.f, c1 = 0.f, c2 = 0.f;
    float d0 = 0.f, d1 = 0.f, d2 = 0.f;
    int i = p0;
    for (; i + 4 <= p1; i += 4) {
        const int e0 = eid[i], e1 = eid[i + 1], e2 = eid[i + 2], e3 = eid[i + 3];
        const unsigned short* r0 = Hb + (long)e0 * HD;
        const unsigned short* r1 = Hb + (long)e1 * HD;
        const unsigned short* r2 = Hb + (long)e2 * HD;
        const unsigned short* r3 = Hb + (long)e3 * HD;
        a0 += b2f(r0[lane]);
        b0 += b2f(r1[lane]);
        c0 += b2f(r2[lane]);
        d0 += b2f(r3[lane]);
        a1 += b2f(r0[64 + lane]);
        b1 += b2f(r1[64 + lane]);
        c1 += b2f(r2[64 + lane]);
        d1 += b2f(r3[64 + lane]);
        if (lane < 32) {
            a2 += b2f(r0[128 + lane]);
            b2 += b2f(r1[128 + lane]);
            c2 += b2f(r2[128 + lane]);
            d2 += b2f(r3[128 + lane]);
        }
    }
    for (; i + 2 <= p1; i += 2) {
        const int e0 = eid[i], e1 = eid[i + 1];
        const unsigned short* r0 = Hb + (long)e0 * HD;
        const unsigned short* r1 = Hb + (long)e1 * HD;
        a0 += b2f(r0[lane]);
        b0 += b2f(r1[lane]);
        a1 += b2f(r0[64 + lane]);
        b1 += b2f(r1[64 + lane]);
        if (lane < 32) {
            a2 += b2f(r0[128 + lane]);
            b2 += b2f(r1[128 + lane]);
        }
    }
    if (i < p1) {
        const unsigned short* r0 = Hb + (long)eid[i] * HD;
        a0 += b2f(r0[lane]);
        a1 += b2f(r0[64 + lane]);
        if (lane < 32) a2 += b2f(r0[128 + lane]);
    }
    a0 += b0 + c0 + d0;
    a1 += b1 + c1 + d1;
    a2 += b2 + c2 + d2;

    const long sb = n * HD;
    if (FINAL) {
        float s = a0 + a1 + a2;
        #pragma unroll
        for (int off = 32; off > 0; off >>= 1) s += __shfl_xor(s, off, 64);
        if (s == 0.f) {
            S[sb + lane]      = x[sb + lane];
            S[sb + 64 + lane] = x[sb + 64 + lane];
            if (lane < 32) S[sb + 128 + lane] = x[sb + 128 + lane];
            return;
        }
        S[sb + lane]      = a0;
        S[sb + 64 + lane] = a1;
        if (lane < 32) S[sb + 128 + lane] = a2;
    } else {
        Sb[sb + lane]      = f2b(a0);
        Sb[sb + 64 + lane] = f2b(a1);
        if (lane < 32) Sb[sb + 128 + lane] = f2b(a2);
    }
}

// ============================ MFMA update, iter 1 ==========================
// Hb[e] = bf16(relu(Hb[e] + Wh @ (Sb[src[e]] - Hb[e^1]) + bh))
// (Hb still holds H0 = h0.)  Full 10-deep prefetch of both gather streams.
__global__ __launch_bounds__(512, 4)
void k_updm1(const unsigned short* __restrict__ Sb,
             const int* __restrict__ src,
             const float* __restrict__ Wh, const float* __restrict__ bh,
             unsigned short* __restrict__ Hb)
{
    __shared__ unsigned short Whl[HD * WHP];   // 52480 B, [h][k] bf16

    const int t = threadIdx.x;
    for (int i = t * 4; i < HD * HD; i += 2048) {
        const int h = i / HD, k = i % HD;
        const float4 wv = *(const float4*)(Wh + h * HD + k);
        *(ushort4*)&Whl[h * WHP + k] =
            make_ushort4(f2b(wv.x), f2b(wv.y), f2b(wv.z), f2b(wv.w));
    }
    __syncthreads();

    const int  w    = t >> 6;
    const int  lane = t & 63;
    const int  cl   = lane & 15;     // A-row / B-col / C-col selector
    const int  kq   = lane >> 4;     // k-group 0..3
    const long base = (long)blockIdx.x * TM + w * 16;

    const long eA  = base + cl;
    const long eAs = (eA < E_EDGES) ? eA : 0;
    const int  sA  = src[eAs];
    const unsigned short* sbrow = Sb + (long)sA * HD + kq * 4;
    const unsigned short* rvrow = Hb + (eAs ^ 1) * HD + kq * 4;

    // full-depth prefetch: issue all 20 loads, waits resolve incrementally
    ushort4 ps[10], pr[10];
    #pragma unroll
    for (int c = 0; c < 10; ++c) {
        ps[c] = *(const ushort4*)(sbrow + c * KC);
        pr[c] = *(const ushort4*)(rvrow + c * KC);
    }

    v4f acc[10];
    #pragma unroll
    for (int n = 0; n < 10; ++n) acc[n] = (v4f){0.f, 0.f, 0.f, 0.f};

    #pragma unroll
    for (int c = 0; c < 10; ++c) {
        const v4s a = mdiff(ps[c], pr[c]);
        #pragma unroll
        for (int n = 0; n < 10; ++n) {
            const v4s b = *(const v4s*)&Whl[(n * 16 + cl) * WHP + c * KC + kq * 4];
            acc[n] = __builtin_amdgcn_mfma_f32_16x16x16bf16_1k(a, b, acc[n], 0, 0, 0);
        }
    }

    #pragma unroll
    for (int n = 0; n < 10; ++n) {
        const int col = n * 16 + cl;
        const float bb = bh[col];
        #pragma unroll
        for (int rr = 0; rr < 4; ++rr) {
            const long e = base + kq * 4 + rr;
            if (e < E_EDGES) {
                unsigned short* hp = Hb + e * HD + col;
                float v = b2f(*hp) + acc[n][rr] + bb;
                v = v > 0.f ? v : 0.f;
                *hp = f2b(v);
            }
        }
    }
}

// ============================ MFMA update, iter 2 ==========================
// DEFERRED-h0: Wh K-loop first (acc in AGPR, full 10-deep prefetch), then
// per-n epilogue (software-pipelined 1 ahead): q = ea @ Wi_e^T (Wieb frag) +
// Pb gather + fused relu/store.
__global__ __launch_bounds__(512, 4)
void k_updm2(const unsigned short* __restrict__ Sb,
             const float* __restrict__ ea, const int* __restrict__ src,
             const unsigned short* __restrict__ Wieb,
             const float* __restrict__ Wh, const float* __restrict__ bh,
             const unsigned short* __restrict__ Pb,
             unsigned short* __restrict__ Hb)
{
    __shared__ unsigned short Whl[HD * WHP];    // 52480 B

    const int t = threadIdx.x;
    for (int i = t * 4; i < HD * HD; i += 2048) {
        const int h = i / HD, k = i % HD;
        const float4 wv = *(const float4*)(Wh + h * HD + k);
        *(ushort4*)&Whl[h * WHP + k] =
            make_ushort4(f2b(wv.x), f2b(wv.y), f2b(wv.z), f2b(wv.w));
    }
    __syncthreads();

    const int  w    = t >> 6;
    const int  lane = t & 63;
    const int  cl   = lane & 15;
    const int  kq   = lane >> 4;
    const long base = (long)blockIdx.x * TM + w * 16;

    const long eA  = base + cl;
    const long eAs = (eA < E_EDGES) ? eA : 0;
    const int  sA  = src[eAs];
    const unsigned short* sbrow = Sb + (long)sA * HD + kq * 4;
    const unsigned short* rvrow = Hb + (eAs ^ 1) * HD + kq * 4;

    // full-depth prefetch of both gather streams
    ushort4 ps[10], pr[10];
    #pragma unroll
    for (int c = 0; c < 10; ++c) {
        ps[c] = *(const ushort4*)(sbrow + c * KC);
        pr[c] = *(const ushort4*)(rvrow + c * KC);
    }

    v4f acc[10];
    #pragma unroll
    for (int n = 0; n < 10; ++n) acc[n] = (v4f){0.f, 0.f, 0.f, 0.f};

    #pragma unroll
    for (int c = 0; c < 10; ++c) {
        const v4s a = mdiff(ps[c], pr[c]);
        #pragma unroll
        for (int n = 0; n < 10; ++n) {
            const v4s b = *(const v4s*)&Whl[(n * 16 + cl) * WHP + c * KC + kq * 4];
            acc[n] = __builtin_amdgcn_mfma_f32_16x16x16bf16_1k(a, b, acc[n], 0, 0, 0);
        }
    }
    // All rev-row (Hb) reads issued above; stores below are same-wave ordered.

    // ---- epilogue: per-n fused Q + Pb gather + store, pipelined 1 ahead ----
    v4s aq;
    {
        const float* earow = ea + eAs * BD;
        if (kq < 3) {
            #pragma unroll
            for (int j = 0; j < 4; ++j) aq[j] = (short)f2b(earow[kq * 4 + j]);
        } else {
            aq[0] = (short)f2b(earow[12]);
            aq[1] = (short)f2b(earow[13]);
            aq[2] = 0; aq[3] = 0;
        }
    }
    int srcC[4];
    #pragma unroll
    for (int rr = 0; rr < 4; ++rr) {
        const long e = base + kq * 4 + rr;
        srcC[rr] = src[(e < E_EDGES) ? e : 0];
    }

    v4s bq0 = *(const v4s*)&Wieb[cl * 16 + kq * 4];
    unsigned short pv0[4];
    #pragma unroll
    for (int rr = 0; rr < 4; ++rr) pv0[rr] = Pb[(long)srcC[rr] * HD + cl];

    #pragma unroll
    for (int n = 0; n < 10; ++n) {
        const int col = n * 16 + cl;
        const v4s bqc = bq0;
        unsigned short pvc[4];
        #pragma unroll
        for (int rr = 0; rr < 4; ++rr) pvc[rr] = pv0[rr];
        if (n < 9) {
            const int coln = (n + 1) * 16 + cl;
            bq0 = *(const v4s*)&Wieb[coln * 16 + kq * 4];
            #pragma unroll
            for (int rr = 0; rr < 4; ++rr) pv0[rr] = Pb[(long)srcC[rr] * HD + coln];
        }
        const v4f q = __builtin_amdgcn_mfma_f32_16x16x16bf16_1k(
                          aq, bqc, (v4f){0.f, 0.f, 0.f, 0.f}, 0, 0, 0);
        const float bb = bh[col];
        #pragma unroll
        for (int rr = 0; rr < 4; ++rr) {
            const long e = base + kq * 4 + rr;
            if (e < E_EDGES) {
                float h0 = b2f(pvc[rr]) + q[rr];
                h0 = h0 > 0.f ? h0 : 0.f;
                float v = h0 + acc[n][rr] + bb;
                v = v > 0.f ? v : 0.f;
                Hb[e * HD + col] = f2b(v);
            }
        }
    }
}

// ============================ output =======================================
__global__ __launch_bounds__(256, 3)
void k_out(const float* __restrict__ x, const float* __restrict__ Mg,
           const float* __restrict__ Wo, const float* __restrict__ bo,
           float* __restrict__ out)
{
    __shared__ float At[KC][TE + 4];
    __shared__ float Wt[KC][WP];

    const int  t    = threadIdx.x;
    const long base = (long)blockIdx.x * TE;
    const int  se  = t >> 2;
    const int  skq = t & 3;
    const long gn  = base + se;
    const bool ev  = gn < N_NODES;
    const long gnc = ev ? gn : 0;
    const float* xrow = x  + gnc * HD;
    const float* mrow = Mg + gnc * HD;
    const int tr = t >> 4, tc = t & 15;

    float acc[4][10];
    #pragma unroll
    for (int i = 0; i < 4; ++i)
        #pragma unroll
        for (int j = 0; j < 10; ++j) acc[i][j] = 0.f;

    for (int c = 0; c < KO / KC; ++c) {
        const int k0 = c * KC;
        __syncthreads();
        {
            const int kb = k0 + skq * 4;
            const float4 v = (kb < HD) ? *(const float4*)(xrow + kb)
                                       : *(const float4*)(mrow + (kb - HD));
            At[skq * 4 + 0][se] = v.x;
            At[skq * 4 + 1][se] = v.y;
            At[skq * 4 + 2][se] = v.z;
            At[skq * 4 + 3][se] = v.w;
        }
        for (int i = t; i < HD * KC; i += 256) {
            const int kk = i & (KC - 1);
            const int h  = i >> 4;
            Wt[kk][h] = Wo[h * KO + k0 + kk];
        }
        __syncthreads();
        gemm_chunk(acc, At, Wt, tr, tc);
    }
    #pragma unroll
    for (int i = 0; i < 4; ++i) {
        const long n = base + tr * 4 + i;
        if (n >= N_NODES) break;
        float* op = out + n * HD + tc * 10;
        #pragma unroll
        for (int j = 0; j < 10; j += 2) {
            float v0 = acc[i][j]     + bo[tc * 10 + j];
            float v1 = acc[i][j + 1] + bo[tc * 10 + j + 1];
            v0 = v0 > 0.f ? v0 : 0.f;
            v1 = v1 > 0.f ? v1 : 0.f;
            *(float2*)(op + j) = make_float2(v0, v1);
        }
    }
}

// ---------------------------------------------------------------------------
extern "C" void kernel_launch(void* const* d_in, const int* in_sizes, int n_in,
                              void* d_out, int out_size, void* d_ws, size_t ws_size,
                              hipStream_t stream)
{
    const float* x  = (const float*)d_in[0];
    const float* ea = (const float*)d_in[1];
    const int*   ei = (const int*)d_in[2];
    const float* Wi = (const float*)d_in[4];
    const float* bi = (const float*)d_in[5];
    const float* Wh = (const float*)d_in[6];
    const float* bh = (const float*)d_in[7];
    const float* Wo = (const float*)d_in[8];
    const float* bo = (const float*)d_in[9];
    float* out = (float*)d_out;

    const int* src = ei;
    const int* dst = ei + E_EDGES;

    const int gM  = (E_EDGES + TM - 1) / TM;      // 3907
    const int gN  = (N_NODES + TE - 1) / TE;      // 782
    const int gF  = (N_NODES + 3) / 4;            // 12500
    const int gEe = (E_EDGES + 255) / 256;        // 1954

    // ws: Hb bf16 (160e6) | Mf fp32 (32e6) | CSR (~2.6e6) | Wieb (5 KB)
    char* w = (char*)d_ws;
    unsigned short* Hb  = (unsigned short*)(w);
    float* Mf   = (float*)(w + 160000000);
    int*   ptr  = (int*)  (w + 192000000);
    int*   cnt  = (int*)  (w + 192200016);
    int*   cur  = (int*)  (w + 192400016);
    int*   eid  = (int*)  (w + 192600016);
    unsigned short* Wieb = (unsigned short*)(w + 194600064);
    // d_out hosts Pb (16e6) + Sb (16e6) until k_out.
    unsigned short* Pb = (unsigned short*)d_out;
    unsigned short* Sb = (unsigned short*)((char*)d_out + 16000000);

    k_zero<<<(100000 + 1023) / 1024, 256, 0, stream>>>((float*)cnt, 100000);
    k_csr_count<<<gEe, 256, 0, stream>>>(dst, cnt);
    k_csr_scan<<<1, 1024, 0, stream>>>(cnt, ptr);
    k_csr_fill<<<gEe, 256, 0, stream>>>(dst, ptr, cur, eid);

    k_nodeproj<<<gN, 256, 0, stream>>>(x, Wi, bi, Pb, Wieb);
    k_h0m<<<gM, 512, 0, stream>>>(ea, src, Wieb, Pb, Hb);                 // H0
    k_segb<0><<<gF, 256, 0, stream>>>(Hb, ptr, eid, x, Sb, nullptr);      // S0
    k_updm1<<<gM, 512, 0, stream>>>(Sb, src, Wh, bh, Hb);                 // H1
    k_segb<0><<<gF, 256, 0, stream>>>(Hb, ptr, eid, x, Sb, nullptr);      // S1
    k_updm2<<<gM, 512, 0, stream>>>(Sb, ea, src, Wieb, Wh, bh, Pb, Hb);   // H2
    k_segb<1><<<gF, 256, 0, stream>>>(Hb, ptr, eid, x, nullptr, Mf);      // M
    k_out<<<gN, 256, 0, stream>>>(x, Mf, Wo, bo, out);
}

// Round 9
// 949.014 us; speedup vs baseline: 1.6642x; 1.0285x over previous
//
#include <hip/hip_runtime.h>

// Chemprop BondMessagePassing, DEPTH=3, eval mode.
// R15 RESUBMIT (R8 bench was an infra failure: "MI355X container failed
// twice" — source never ran; re-running byte-identical for clean attribution).
// R15: epilogue batch-prefetch round (R7 post-mortem: updm epilogues contain
//   ~10 serial L2/L3-latency stalls each — own-row h0 reads in updm1, Pb
//   gathers in updm2; with 3.4 waves/SIMD these are uncovered).
//  - k_updm1/k_updm2: after the K-loop, issue the entire epilogue load batch
//    (40 scalar u16 + frags) in one go, then compute+store. Live set stays
//    under the (512,4) 128-reg budget (acc 40 AGPR + 40 u16 + misc).
//  - Whb: Wh pre-converted to bf16 in padded [h][WHP] layout by k_wcvt (25
//    blocks); updm LDS staging = pure ushort4 copy (no f2b, half the bytes).
//  - k_segb: 8x main unroll (24 in-flight rows) + 4/2/1 tails.
// ws: Hb bf16 @0 (160e6) | Mf fp32 @160e6 (32e6) | CSR @192e6 |
//     Wieb @194600064 (5 KB) | Whb @194605184 (52480 B). All < 195e6 proven.
// d_out hosts Pb(16e6)+Sb(16e6) until k_out.

#define E_EDGES 500000
#define N_NODES 50000
#define HD      160
#define BD      14
#define K1      174
#define KO      320

#define TE 64
#define KC 16
#define NC2 (HD / KC)   // 10
#define WP  (HD + 8)    // Wt stride (vector kernels)

#define TM   128        // edges per MFMA block (8 waves x 16)
#define WHP  164        // Whl padded k-stride (shorts)

typedef __attribute__((ext_vector_type(4))) short v4s;
typedef __attribute__((ext_vector_type(4))) float v4f;

// ---- bf16 helpers (RNE) ----
__device__ __forceinline__ unsigned short f2b(float v) {
    unsigned u = __float_as_uint(v);
    u += 0x7FFFu + ((u >> 16) & 1u);
    return (unsigned short)(u >> 16);
}
__device__ __forceinline__ float b2f(unsigned short h) {
    return __uint_as_float(((unsigned)h) << 16);
}

__device__ __forceinline__ v4s mdiff(ushort4 s, ushort4 r) {
    v4s a;
    a[0] = (short)f2b(b2f(s.x) - b2f(r.x));
    a[1] = (short)f2b(b2f(s.y) - b2f(r.y));
    a[2] = (short)f2b(b2f(s.z) - b2f(r.z));
    a[3] = (short)f2b(b2f(s.w) - b2f(r.w));
    return a;
}

// ---------------------------------------------------------------------------
__global__ void k_zero(float* __restrict__ p, long n)
{
    const long i = (long)blockIdx.x * 1024 + (long)threadIdx.x * 4;
    if (i + 3 < n) *(float4*)(p + i) = make_float4(0.f, 0.f, 0.f, 0.f);
}

// ---- Wh -> bf16 padded layout (one-time) ----
__global__ void k_wcvt(const float* __restrict__ Wh, unsigned short* __restrict__ Whb)
{
    const int i = blockIdx.x * 256 + threadIdx.x;   // quad index, 6400 total
    if (i < HD * HD / 4) {
        const int h = (i * 4) / HD, k = (i * 4) % HD;
        const float4 wv = *(const float4*)(Wh + h * HD + k);
        *(ushort4*)&Whb[h * WHP + k] =
            make_ushort4(f2b(wv.x), f2b(wv.y), f2b(wv.z), f2b(wv.w));
    }
}

// ---------------------------------------------------------------------------
__device__ __forceinline__
void gemm_chunk(float acc[4][10], const float At[KC][TE + 4],
                const float Wt[KC][WP], int tr, int tc)
{
    #pragma unroll
    for (int k = 0; k < KC; ++k) {
        const float4 a  = *(const float4*)&At[k][tr * 4];
        const float* wp = &Wt[k][tc * 10];
        float w[10];
        #pragma unroll
        for (int j = 0; j < 10; j += 2) {
            const float2 w2 = *(const float2*)(wp + j);
            w[j] = w2.x; w[j + 1] = w2.y;
        }
        #pragma unroll
        for (int j = 0; j < 10; ++j) {
            acc[0][j] = fmaf(a.x, w[j], acc[0][j]);
            acc[1][j] = fmaf(a.y, w[j], acc[1][j]);
            acc[2][j] = fmaf(a.z, w[j], acc[2][j]);
            acc[3][j] = fmaf(a.w, w[j], acc[3][j]);
        }
    }
}

// ============================ CSR build ====================================
__global__ void k_csr_count(const int* __restrict__ dst, int* __restrict__ cnt)
{
    const int e = blockIdx.x * 256 + threadIdx.x;
    if (e < E_EDGES) atomicAdd(&cnt[dst[e]], 1);
}

#define BPT 49
__global__ __launch_bounds__(1024)
void k_csr_scan(const int* __restrict__ cnt, int* __restrict__ ptr)
{
    __shared__ int part[1024];
    const int t  = threadIdx.x;
    const int lo = t * BPT;
    const int hi = min(lo + BPT, N_NODES);
    int s = 0;
    for (int i = lo; i < hi; ++i) s += cnt[i];
    part[t] = s;
    __syncthreads();
    for (int off = 1; off < 1024; off <<= 1) {
        int v = 0;
        if (t >= off) v = part[t - off];
        __syncthreads();
        if (t >= off) part[t] += v;
        __syncthreads();
    }
    int run = (t == 0) ? 0 : part[t - 1];
    for (int i = lo; i < hi; ++i) { ptr[i] = run; run += cnt[i]; }
    if (t == 1023) ptr[N_NODES] = part[1023];
}

__global__ void k_csr_fill(const int* __restrict__ dst, const int* __restrict__ ptr,
                           int* __restrict__ cur, int* __restrict__ eid)
{
    const int e = blockIdx.x * 256 + threadIdx.x;
    if (e < E_EDGES) {
        const int d   = dst[e];
        const int pos = atomicAdd(&cur[d], 1);
        eid[ptr[d] + pos] = e;
    }
}

// ============================ node projection ==============================
// Pb[n] = bf16(Wi_x @ x[n] + bi)  (NO relu). Block 0 also fills the Wieb
// table: Wieb[col*16 + k'] = bf16(Wi[col][HD+k']) for k'<14, else 0.
__global__ __launch_bounds__(256, 2)
void k_nodeproj(const float* __restrict__ x, const float* __restrict__ Wi,
                const float* __restrict__ bi, unsigned short* __restrict__ Pb,
                unsigned short* __restrict__ Wieb)
{
    __shared__ float At[KC][TE + 4];
    __shared__ float Wt[KC][WP];

    const int  t    = threadIdx.x;
    const long base = (long)blockIdx.x * TE;
    const int  se  = t >> 2;
    const int  skq = t & 3;
    const long gn  = base + se;
    const long gnc = (gn < N_NODES) ? gn : 0;
    const float* xrow = x + gnc * HD;
    const int tr = t >> 4, tc = t & 15;

    if (blockIdx.x == 0 && t < HD) {
        const float* wr = Wi + (long)t * K1 + HD;
        unsigned short* wo = Wieb + t * 16;
        #pragma unroll
        for (int k = 0; k < 16; ++k) wo[k] = (k < BD) ? f2b(wr[k]) : (unsigned short)0;
    }

    float acc[4][10];
    #pragma unroll
    for (int i = 0; i < 4; ++i)
        #pragma unroll
        for (int j = 0; j < 10; ++j) acc[i][j] = 0.f;

    for (int c = 0; c < NC2; ++c) {
        const int k0 = c * KC;
        __syncthreads();
        {
            const float4 v = *(const float4*)(xrow + k0 + skq * 4);
            At[skq * 4 + 0][se] = v.x;
            At[skq * 4 + 1][se] = v.y;
            At[skq * 4 + 2][se] = v.z;
            At[skq * 4 + 3][se] = v.w;
        }
        for (int i = t; i < HD * KC; i += 256) {
            const int kk = i & (KC - 1);
            const int h  = i >> 4;
            Wt[kk][h] = Wi[h * K1 + k0 + kk];
        }
        __syncthreads();
        gemm_chunk(acc, At, Wt, tr, tc);
    }
    #pragma unroll
    for (int i = 0; i < 4; ++i) {
        const long n = base + tr * 4 + i;
        if (n >= N_NODES) break;
        unsigned short* pp = Pb + n * HD + tc * 10;
        #pragma unroll
        for (int j = 0; j < 10; j += 2) {
            const float v0 = acc[i][j]     + bi[tc * 10 + j];
            const float v1 = acc[i][j + 1] + bi[tc * 10 + j + 1];
            *(ushort2*)(pp + j) = make_ushort2(f2b(v0), f2b(v1));
        }
    }
}

// ============================ H0 (MFMA, no LDS) ============================
// Hb[e] = bf16(relu(Pb[src[e]] + ea[e] @ Wi_e^T)), 16 edges/wave.
// All Pb gathers + Wieb frags issued upfront.
__global__ __launch_bounds__(512, 4)
void k_h0m(const float* __restrict__ ea, const int* __restrict__ src,
           const unsigned short* __restrict__ Wieb,
           const unsigned short* __restrict__ Pb,
           unsigned short* __restrict__ Hb)
{
    const int  t    = threadIdx.x;
    const int  w    = t >> 6;
    const int  lane = t & 63;
    const int  cl   = lane & 15;
    const int  kq   = lane >> 4;
    const long base = (long)blockIdx.x * TM + w * 16;

    const long eA  = base + cl;
    const long eAs = (eA < E_EDGES) ? eA : 0;

    // A-frag from ea row (k' = kq*4+j; guard k' < BD without OOB reads)
    v4s aq;
    {
        const float* earow = ea + eAs * BD;
        if (kq < 3) {
            #pragma unroll
            for (int j = 0; j < 4; ++j) aq[j] = (short)f2b(earow[kq * 4 + j]);
        } else {
            aq[0] = (short)f2b(earow[12]);
            aq[1] = (short)f2b(earow[13]);
            aq[2] = 0; aq[3] = 0;
        }
    }
    int srcC[4];
    #pragma unroll
    for (int rr = 0; rr < 4; ++rr) {
        const long e = base + kq * 4 + rr;
        srcC[rr] = src[(e < E_EDGES) ? e : 0];
    }

    // issue ALL gathers + table loads upfront
    unsigned short pvv[10][4];
    v4s bqa[10];
    #pragma unroll
    for (int n = 0; n < 10; ++n) {
        const int col = n * 16 + cl;
        bqa[n] = *(const v4s*)&Wieb[col * 16 + kq * 4];
        #pragma unroll
        for (int rr = 0; rr < 4; ++rr)
            pvv[n][rr] = Pb[(long)srcC[rr] * HD + col];
    }

    #pragma unroll
    for (int n = 0; n < 10; ++n) {
        const int col = n * 16 + cl;
        const v4f q = __builtin_amdgcn_mfma_f32_16x16x16bf16_1k(
                          aq, bqa[n], (v4f){0.f, 0.f, 0.f, 0.f}, 0, 0, 0);
        #pragma unroll
        for (int rr = 0; rr < 4; ++rr) {
            const long e = base + kq * 4 + rr;
            if (e < E_EDGES) {
                float v = b2f(pvv[n][rr]) + q[rr];
                v = v > 0.f ? v : 0.f;
                Hb[e * HD + col] = f2b(v);
            }
        }
    }
}

// ============================ segment sum ==================================
// FINAL=0: write bf16 Sb. FINAL=1: write fp32 S with sum==0 -> x fallback.
// 8x main unroll (24 in-flight rows) + 4/2/1 tails.
template <int FINAL>
__global__ void k_segb(const unsigned short* __restrict__ Hb,
                       const int* __restrict__ ptr, const int* __restrict__ eid,
                       const float* __restrict__ x,
                       unsigned short* __restrict__ Sb, float* __restrict__ S)
{
    const int  lane = threadIdx.x & 63;
    const int  w    = threadIdx.x >> 6;
    const long n    = (long)blockIdx.x * 4 + w;
    if (n >= N_NODES) return;
    const int p0 = ptr[n], p1 = ptr[n + 1];
    float a0 = 0.f, a1 = 0.f, a2 = 0.f;
    float b0 = 0.f, b1 = 0.f, b2 = 0.f;
    float c0 = 0.f, c1 = 0.f, c2 = 0.f;
    float d0 = 0.f, d1 = 0.f, d2 = 0.f;
    int i = p0;
    for (; i + 8 <= p1; i += 8) {
        const unsigned short* r0 = Hb + (long)eid[i]     * HD;
        const unsigned short* r1 = Hb + (long)eid[i + 1] * HD;
        const unsigned short* r2 = Hb + (long)eid[i + 2] * HD;
        const unsigned short* r3 = Hb + (long)eid[i + 3] * HD;
        const unsigned short* r4 = Hb + (long)eid[i + 4] * HD;
        const unsigned short* r5 = Hb + (long)eid[i + 5] * HD;
        const unsigned short* r6 = Hb + (long)eid[i + 6] * HD;
        const unsigned short* r7 = Hb + (long)eid[i + 7] * HD;
        a0 += b2f(r0[lane]); b0 += b2f(r1[lane]);
        c0 += b2f(r2[lane]); d0 += b2f(r3[lane]);
        a0 += b2f(r4[lane]); b0 += b2f(r5[lane]);
        c0 += b2f(r6[lane]); d0 += b2f(r7[lane]);
        a1 += b2f(r0[64 + lane]); b1 += b2f(r1[64 + lane]);
        c1 += b2f(r2[64 + lane]); d1 += b2f(r3[64 + lane]);
        a1 += b2f(r4[64 + lane]); b1 += b2f(r5[64 + lane]);
        c1 += b2f(r6[64 + lane]); d1 += b2f(r7[64 + lane]);
        if (lane < 32) {
            a2 += b2f(r0[128 + lane]); b2 += b2f(r1[128 + lane]);
            c2 += b2f(r2[128 + lane]); d2 += b2f(r3[128 + lane]);
            a2 += b2f(r4[128 + lane]); b2 += b2f(r5[128 + lane]);
            c2 += b2f(r6[128 + lane]); d2 += b2f(r7[128 + lane]);
        }
    }
    for (; i + 4 <= p1; i += 4) {
        const unsigned short* r0 = Hb + (long)eid[i]     * HD;
        const unsigned short* r1 = Hb + (long)eid[i + 1] * HD;
        const unsigned short* r2 = Hb + (long)eid[i + 2] * HD;
        const unsigned short* r3 = Hb + (long)eid[i + 3] * HD;
        a0 += b2f(r0[lane]); b0 += b2f(r1[lane]);
        c0 += b2f(r2[lane]); d0 += b2f(r3[lane]);
        a1 += b2f(r0[64 + lane]); b1 += b2f(r1[64 + lane]);
        c1 += b2f(r2[64 + lane]); d1 += b2f(r3[64 + lane]);
        if (lane < 32) {
            a2 += b2f(r0[128 + lane]); b2 += b2f(r1[128 + lane]);
            c2 += b2f(r2[128 + lane]); d2 += b2f(r3[128 + lane]);
        }
    }
    for (; i + 2 <= p1; i += 2) {
        const unsigned short* r0 = Hb + (long)eid[i]     * HD;
        const unsigned short* r1 = Hb + (long)eid[i + 1] * HD;
        a0 += b2f(r0[lane]); b0 += b2f(r1[lane]);
        a1 += b2f(r0[64 + lane]); b1 += b2f(r1[64 + lane]);
        if (lane < 32) {
            a2 += b2f(r0[128 + lane]); b2 += b2f(r1[128 + lane]);
        }
    }
    if (i < p1) {
        const unsigned short* r0 = Hb + (long)eid[i] * HD;
        a0 += b2f(r0[lane]);
        a1 += b2f(r0[64 + lane]);
        if (lane < 32) a2 += b2f(r0[128 + lane]);
    }
    a0 += b0 + c0 + d0;
    a1 += b1 + c1 + d1;
    a2 += b2 + c2 + d2;

    const long sb = n * HD;
    if (FINAL) {
        float s = a0 + a1 + a2;
        #pragma unroll
        for (int off = 32; off > 0; off >>= 1) s += __shfl_xor(s, off, 64);
        if (s == 0.f) {
            S[sb + lane]      = x[sb + lane];
            S[sb + 64 + lane] = x[sb + 64 + lane];
            if (lane < 32) S[sb + 128 + lane] = x[sb + 128 + lane];
            return;
        }
        S[sb + lane]      = a0;
        S[sb + 64 + lane] = a1;
        if (lane < 32) S[sb + 128 + lane] = a2;
    } else {
        Sb[sb + lane]      = f2b(a0);
        Sb[sb + 64 + lane] = f2b(a1);
        if (lane < 32) Sb[sb + 128 + lane] = f2b(a2);
    }
}

// ============================ MFMA update, iter 1 ==========================
// Hb[e] = bf16(relu(Hb[e] + Wh @ (Sb[src[e]] - Hb[e^1]) + bh))
// (Hb still holds H0 = h0.)  Full K-prefetch; epilogue h0 batch-prefetched.
__global__ __launch_bounds__(512, 4)
void k_updm1(const unsigned short* __restrict__ Sb,
             const int* __restrict__ src,
             const unsigned short* __restrict__ Whb, const float* __restrict__ bh,
             unsigned short* __restrict__ Hb)
{
    __shared__ unsigned short Whl[HD * WHP];   // 52480 B, [h][k] bf16

    const int t = threadIdx.x;
    for (int i = t * 4; i < HD * WHP; i += 2048)
        *(ushort4*)&Whl[i] = *(const ushort4*)&Whb[i];
    __syncthreads();

    const int  w    = t >> 6;
    const int  lane = t & 63;
    const int  cl   = lane & 15;     // A-row / B-col / C-col selector
    const int  kq   = lane >> 4;     // k-group 0..3
    const long base = (long)blockIdx.x * TM + w * 16;

    const long eA  = base + cl;
    const long eAs = (eA < E_EDGES) ? eA : 0;
    const int  sA  = src[eAs];
    const unsigned short* sbrow = Sb + (long)sA * HD + kq * 4;
    const unsigned short* rvrow = Hb + (eAs ^ 1) * HD + kq * 4;

    // full-depth prefetch: issue all 20 loads, waits resolve incrementally
    ushort4 ps[10], pr[10];
    #pragma unroll
    for (int c = 0; c < 10; ++c) {
        ps[c] = *(const ushort4*)(sbrow + c * KC);
        pr[c] = *(const ushort4*)(rvrow + c * KC);
    }

    v4f acc[10];
    #pragma unroll
    for (int n = 0; n < 10; ++n) acc[n] = (v4f){0.f, 0.f, 0.f, 0.f};

    #pragma unroll
    for (int c = 0; c < 10; ++c) {
        const v4s a = mdiff(ps[c], pr[c]);
        #pragma unroll
        for (int n = 0; n < 10; ++n) {
            const v4s b = *(const v4s*)&Whl[(n * 16 + cl) * WHP + c * KC + kq * 4];
            acc[n] = __builtin_amdgcn_mfma_f32_16x16x16bf16_1k(a, b, acc[n], 0, 0, 0);
        }
    }

    // ---- epilogue: batch-prefetch own-row h0 (40 u16), then compute+store ----
    long eC[4];
    #pragma unroll
    for (int rr = 0; rr < 4; ++rr) {
        const long e = base + kq * 4 + rr;
        eC[rr] = (e < E_EDGES) ? e : 0;
    }
    unsigned short hv[10][4];
    #pragma unroll
    for (int n = 0; n < 10; ++n)
        #pragma unroll
        for (int rr = 0; rr < 4; ++rr)
            hv[n][rr] = Hb[eC[rr] * HD + n * 16 + cl];

    #pragma unroll
    for (int n = 0; n < 10; ++n) {
        const int col = n * 16 + cl;
        const float bb = bh[col];
        #pragma unroll
        for (int rr = 0; rr < 4; ++rr) {
            const long e = base + kq * 4 + rr;
            if (e < E_EDGES) {
                float v = b2f(hv[n][rr]) + acc[n][rr] + bb;
                v = v > 0.f ? v : 0.f;
                Hb[e * HD + col] = f2b(v);
            }
        }
    }
}

// ============================ MFMA update, iter 2 ==========================
// DEFERRED-h0: Wh K-loop first, then epilogue batch: all Pb gathers + Wieb
// frags + aq issued at once, then per-n Q-MFMA + fused relu/store.
__global__ __launch_bounds__(512, 4)
void k_updm2(const unsigned short* __restrict__ Sb,
             const float* __restrict__ ea, const int* __restrict__ src,
             const unsigned short* __restrict__ Wieb,
             const unsigned short* __restrict__ Whb, const float* __restrict__ bh,
             const unsigned short* __restrict__ Pb,
             unsigned short* __restrict__ Hb)
{
    __shared__ unsigned short Whl[HD * WHP];    // 52480 B

    const int t = threadIdx.x;
    for (int i = t * 4; i < HD * WHP; i += 2048)
        *(ushort4*)&Whl[i] = *(const ushort4*)&Whb[i];
    __syncthreads();

    const int  w    = t >> 6;
    const int  lane = t & 63;
    const int  cl   = lane & 15;
    const int  kq   = lane >> 4;
    const long base = (long)blockIdx.x * TM + w * 16;

    const long eA  = base + cl;
    const long eAs = (eA < E_EDGES) ? eA : 0;
    const int  sA  = src[eAs];
    const unsigned short* sbrow = Sb + (long)sA * HD + kq * 4;
    const unsigned short* rvrow = Hb + (eAs ^ 1) * HD + kq * 4;

    // full-depth prefetch of both gather streams
    ushort4 ps[10], pr[10];
    #pragma unroll
    for (int c = 0; c < 10; ++c) {
        ps[c] = *(const ushort4*)(sbrow + c * KC);
        pr[c] = *(const ushort4*)(rvrow + c * KC);
    }

    v4f acc[10];
    #pragma unroll
    for (int n = 0; n < 10; ++n) acc[n] = (v4f){0.f, 0.f, 0.f, 0.f};

    #pragma unroll
    for (int c = 0; c < 10; ++c) {
        const v4s a = mdiff(ps[c], pr[c]);
        #pragma unroll
        for (int n = 0; n < 10; ++n) {
            const v4s b = *(const v4s*)&Whl[(n * 16 + cl) * WHP + c * KC + kq * 4];
            acc[n] = __builtin_amdgcn_mfma_f32_16x16x16bf16_1k(a, b, acc[n], 0, 0, 0);
        }
    }
    // All rev-row (Hb) reads issued above; stores below are same-wave ordered.

    // ---- epilogue batch: aq + srcC + all Pb gathers + all Wieb frags ----
    v4s aq;
    {
        const float* earow = ea + eAs * BD;
        if (kq < 3) {
            #pragma unroll
            for (int j = 0; j < 4; ++j) aq[j] = (short)f2b(earow[kq * 4 + j]);
        } else {
            aq[0] = (short)f2b(earow[12]);
            aq[1] = (short)f2b(earow[13]);
            aq[2] = 0; aq[3] = 0;
        }
    }
    int srcC[4];
    #pragma unroll
    for (int rr = 0; rr < 4; ++rr) {
        const long e = base + kq * 4 + rr;
        srcC[rr] = src[(e < E_EDGES) ? e : 0];
    }
    unsigned short pvv[10][4];
    v4s bqa[10];
    #pragma unroll
    for (int n = 0; n < 10; ++n) {
        const int col = n * 16 + cl;
        bqa[n] = *(const v4s*)&Wieb[col * 16 + kq * 4];
        #pragma unroll
        for (int rr = 0; rr < 4; ++rr)
            pvv[n][rr] = Pb[(long)srcC[rr] * HD + col];
    }

    #pragma unroll
    for (int n = 0; n < 10; ++n) {
        const int col = n * 16 + cl;
        const v4f q = __builtin_amdgcn_mfma_f32_16x16x16bf16_1k(
                          aq, bqa[n], (v4f){0.f, 0.f, 0.f, 0.f}, 0, 0, 0);
        const float bb = bh[col];
        #pragma unroll
        for (int rr = 0; rr < 4; ++rr) {
            const long e = base + kq * 4 + rr;
            if (e < E_EDGES) {
                float h0 = b2f(pvv[n][rr]) + q[rr];
                h0 = h0 > 0.f ? h0 : 0.f;
                float v = h0 + acc[n][rr] + bb;
                v = v > 0.f ? v : 0.f;
                Hb[e * HD + col] = f2b(v);
            }
        }
    }
}

// ============================ output =======================================
__global__ __launch_bounds__(256, 3)
void k_out(const float* __restrict__ x, const float* __restrict__ Mg,
           const float* __restrict__ Wo, const float* __restrict__ bo,
           float* __restrict__ out)
{
    __shared__ float At[KC][TE + 4];
    __shared__ float Wt[KC][WP];

    const int  t    = threadIdx.x;
    const long base = (long)blockIdx.x * TE;
    const int  se  = t >> 2;
    const int  skq = t & 3;
    const long gn  = base + se;
    const bool ev  = gn < N_NODES;
    const long gnc = ev ? gn : 0;
    const float* xrow = x  + gnc * HD;
    const float* mrow = Mg + gnc * HD;
    const int tr = t >> 4, tc = t & 15;

    float acc[4][10];
    #pragma unroll
    for (int i = 0; i < 4; ++i)
        #pragma unroll
        for (int j = 0; j < 10; ++j) acc[i][j] = 0.f;

    for (int c = 0; c < KO / KC; ++c) {
        const int k0 = c * KC;
        __syncthreads();
        {
            const int kb = k0 + skq * 4;
            const float4 v = (kb < HD) ? *(const float4*)(xrow + kb)
                                       : *(const float4*)(mrow + (kb - HD));
            At[skq * 4 + 0][se] = v.x;
            At[skq * 4 + 1][se] = v.y;
            At[skq * 4 + 2][se] = v.z;
            At[skq * 4 + 3][se] = v.w;
        }
        for (int i = t; i < HD * KC; i += 256) {
            const int kk = i & (KC - 1);
            const int h  = i >> 4;
            Wt[kk][h] = Wo[h * KO + k0 + kk];
        }
        __syncthreads();
        gemm_chunk(acc, At, Wt, tr, tc);
    }
    #pragma unroll
    for (int i = 0; i < 4; ++i) {
        const long n = base + tr * 4 + i;
        if (n >= N_NODES) break;
        float* op = out + n * HD + tc * 10;
        #pragma unroll
        for (int j = 0; j < 10; j += 2) {
            float v0 = acc[i][j]     + bo[tc * 10 + j];
            float v1 = acc[i][j + 1] + bo[tc * 10 + j + 1];
            v0 = v0 > 0.f ? v0 : 0.f;
            v1 = v1 > 0.f ? v1 : 0.f;
            *(float2*)(op + j) = make_float2(v0, v1);
        }
    }
}

// ---------------------------------------------------------------------------
extern "C" void kernel_launch(void* const* d_in, const int* in_sizes, int n_in,
                              void* d_out, int out_size, void* d_ws, size_t ws_size,
                              hipStream_t stream)
{
    const float* x  = (const float*)d_in[0];
    const float* ea = (const float*)d_in[1];
    const int*   ei = (const int*)d_in[2];
    const float* Wi = (const float*)d_in[4];
    const float* bi = (const float*)d_in[5];
    const float* Wh = (const float*)d_in[6];
    const float* bh = (const float*)d_in[7];
    const float* Wo = (const float*)d_in[8];
    const float* bo = (const float*)d_in[9];
    float* out = (float*)d_out;

    const int* src = ei;
    const int* dst = ei + E_EDGES;

    const int gM  = (E_EDGES + TM - 1) / TM;      // 3907
    const int gN  = (N_NODES + TE - 1) / TE;      // 782
    const int gF  = (N_NODES + 3) / 4;            // 12500
    const int gEe = (E_EDGES + 255) / 256;        // 1954

    // ws: Hb bf16 (160e6) | Mf fp32 (32e6) | CSR (~2.6e6) | Wieb | Whb
    char* w = (char*)d_ws;
    unsigned short* Hb  = (unsigned short*)(w);
    float* Mf   = (float*)(w + 160000000);
    int*   ptr  = (int*)  (w + 192000000);
    int*   cnt  = (int*)  (w + 192200016);
    int*   cur  = (int*)  (w + 192400016);
    int*   eid  = (int*)  (w + 192600016);
    unsigned short* Wieb = (unsigned short*)(w + 194600064);
    unsigned short* Whb  = (unsigned short*)(w + 194605184);
    // d_out hosts Pb (16e6) + Sb (16e6) until k_out.
    unsigned short* Pb = (unsigned short*)d_out;
    unsigned short* Sb = (unsigned short*)((char*)d_out + 16000000);

    k_zero<<<(100000 + 1023) / 1024, 256, 0, stream>>>((float*)cnt, 100000);
    k_csr_count<<<gEe, 256, 0, stream>>>(dst, cnt);
    k_wcvt<<<25, 256, 0, stream>>>(Wh, Whb);
    k_csr_scan<<<1, 1024, 0, stream>>>(cnt, ptr);
    k_csr_fill<<<gEe, 256, 0, stream>>>(dst, ptr, cur, eid);

    k_nodeproj<<<gN, 256, 0, stream>>>(x, Wi, bi, Pb, Wieb);
    k_h0m<<<gM, 512, 0, stream>>>(ea, src, Wieb, Pb, Hb);                 // H0
    k_segb<0><<<gF, 256, 0, stream>>>(Hb, ptr, eid, x, Sb, nullptr);      // S0
    k_updm1<<<gM, 512, 0, stream>>>(Sb, src, Whb, bh, Hb);                // H1
    k_segb<0><<<gF, 256, 0, stream>>>(Hb, ptr, eid, x, Sb, nullptr);      // S1
    k_updm2<<<gM, 512, 0, stream>>>(Sb, ea, src, Wieb, Whb, bh, Pb, Hb);  // H2
    k_segb<1><<<gF, 256, 0, stream>>>(Hb, ptr, eid, x, nullptr, Mf);      // M
    k_out<<<gN, 256, 0, stream>>>(x, Mf, Wo, bo, out);
}

// Round 10
// 927.354 us; speedup vs baseline: 1.7031x; 1.0234x over previous
//
#include <hip/hip_runtime.h>

// Chemprop BondMessagePassing, DEPTH=3, eval mode.
// R16: identity-MFMA transpose round (R9 post-mortem: updm/h0m issue ~110
//   VMEM instr/wave, 80 of them scalar 2B gathers/stores forced by the MFMA
//   C-layout; address VALU dominates VALUBusy 27%).
//  - mfma(A, I, C) = A-layout -> C-layout transpose, chained into acc:
//    * updm1 h0: 10 vector own-row loads + 10 I-MFMAs (was 40 scalar loads)
//    * updm2/h0m P: t = mfma(aq, Wie, mfma(pbA, I, 0)) — P-row vector loads
//      from Pb+sA*HD (reuses K-loop sA; was 40 scalar gathers + addr math)
//    * stores: pack bf16 A-frag, I-MFMA transpose, 10x ushort4 (was 40 scalar)
//    I-frag: bqI[j] = (kq*4+j==cl) ? 1.0bf16 : 0. 0*finite=0 -> clamped-row
//    garbage can't leak; fma(1,a,c) = a+c exactly -> numerics unchanged.
//  - Everything else byte-identical to R15/R9.
// ws: Hb bf16 @0 (160e6) | Mf fp32 @160e6 (32e6) | CSR @192e6 |
//     Wieb @194600064 (5 KB) | Whb @194605184 (52480 B). All < 195e6 proven.
// d_out hosts Pb(16e6)+Sb(16e6) until k_out.

#define E_EDGES 500000
#define N_NODES 50000
#define HD      160
#define BD      14
#define K1      174
#define KO      320

#define TE 64
#define KC 16
#define NC2 (HD / KC)   // 10
#define WP  (HD + 8)    // Wt stride (vector kernels)

#define TM   128        // edges per MFMA block (8 waves x 16)
#define WHP  164        // Whl padded k-stride (shorts)

typedef __attribute__((ext_vector_type(4))) short v4s;
typedef __attribute__((ext_vector_type(4))) float v4f;

// ---- bf16 helpers (RNE) ----
__device__ __forceinline__ unsigned short f2b(float v) {
    unsigned u = __float_as_uint(v);
    u += 0x7FFFu + ((u >> 16) & 1u);
    return (unsigned short)(u >> 16);
}
__device__ __forceinline__ float b2f(unsigned short h) {
    return __uint_as_float(((unsigned)h) << 16);
}
// exact truncation for values already bf16-representable (post I-MFMA)
__device__ __forceinline__ unsigned short f2bt(float v) {
    return (unsigned short)(__float_as_uint(v) >> 16);
}

__device__ __forceinline__ v4s mdiff(ushort4 s, ushort4 r) {
    v4s a;
    a[0] = (short)f2b(b2f(s.x) - b2f(r.x));
    a[1] = (short)f2b(b2f(s.y) - b2f(r.y));
    a[2] = (short)f2b(b2f(s.z) - b2f(r.z));
    a[3] = (short)f2b(b2f(s.w) - b2f(r.w));
    return a;
}

// ---------------------------------------------------------------------------
__global__ void k_zero(float* __restrict__ p, long n)
{
    const long i = (long)blockIdx.x * 1024 + (long)threadIdx.x * 4;
    if (i + 3 < n) *(float4*)(p + i) = make_float4(0.f, 0.f, 0.f, 0.f);
}

// ---- Wh -> bf16 padded layout (one-time) ----
__global__ void k_wcvt(const float* __restrict__ Wh, unsigned short* __restrict__ Whb)
{
    const int i = blockIdx.x * 256 + threadIdx.x;   // quad index, 6400 total
    if (i < HD * HD / 4) {
        const int h = (i * 4) / HD, k = (i * 4) % HD;
        const float4 wv = *(const float4*)(Wh + h * HD + k);
        *(ushort4*)&Whb[h * WHP + k] =
            make_ushort4(f2b(wv.x), f2b(wv.y), f2b(wv.z), f2b(wv.w));
    }
}

// ---------------------------------------------------------------------------
__device__ __forceinline__
void gemm_chunk(float acc[4][10], const float At[KC][TE + 4],
                const float Wt[KC][WP], int tr, int tc)
{
    #pragma unroll
    for (int k = 0; k < KC; ++k) {
        const float4 a  = *(const float4*)&At[k][tr * 4];
        const float* wp = &Wt[k][tc * 10];
        float w[10];
        #pragma unroll
        for (int j = 0; j < 10; j += 2) {
            const float2 w2 = *(const float2*)(wp + j);
            w[j] = w2.x; w[j + 1] = w2.y;
        }
        #pragma unroll
        for (int j = 0; j < 10; ++j) {
            acc[0][j] = fmaf(a.x, w[j], acc[0][j]);
            acc[1][j] = fmaf(a.y, w[j], acc[1][j]);
            acc[2][j] = fmaf(a.z, w[j], acc[2][j]);
            acc[3][j] = fmaf(a.w, w[j], acc[3][j]);
        }
    }
}

// ============================ CSR build ====================================
__global__ void k_csr_count(const int* __restrict__ dst, int* __restrict__ cnt)
{
    const int e = blockIdx.x * 256 + threadIdx.x;
    if (e < E_EDGES) atomicAdd(&cnt[dst[e]], 1);
}

#define BPT 49
__global__ __launch_bounds__(1024)
void k_csr_scan(const int* __restrict__ cnt, int* __restrict__ ptr)
{
    __shared__ int part[1024];
    const int t  = threadIdx.x;
    const int lo = t * BPT;
    const int hi = min(lo + BPT, N_NODES);
    int s = 0;
    for (int i = lo; i < hi; ++i) s += cnt[i];
    part[t] = s;
    __syncthreads();
    for (int off = 1; off < 1024; off <<= 1) {
        int v = 0;
        if (t >= off) v = part[t - off];
        __syncthreads();
        if (t >= off) part[t] += v;
        __syncthreads();
    }
    int run = (t == 0) ? 0 : part[t - 1];
    for (int i = lo; i < hi; ++i) { ptr[i] = run; run += cnt[i]; }
    if (t == 1023) ptr[N_NODES] = part[1023];
}

__global__ void k_csr_fill(const int* __restrict__ dst, const int* __restrict__ ptr,
                           int* __restrict__ cur, int* __restrict__ eid)
{
    const int e = blockIdx.x * 256 + threadIdx.x;
    if (e < E_EDGES) {
        const int d   = dst[e];
        const int pos = atomicAdd(&cur[d], 1);
        eid[ptr[d] + pos] = e;
    }
}

// ============================ node projection ==============================
// Pb[n] = bf16(Wi_x @ x[n] + bi)  (NO relu). Block 0 also fills the Wieb
// table: Wieb[col*16 + k'] = bf16(Wi[col][HD+k']) for k'<14, else 0.
__global__ __launch_bounds__(256, 2)
void k_nodeproj(const float* __restrict__ x, const float* __restrict__ Wi,
                const float* __restrict__ bi, unsigned short* __restrict__ Pb,
                unsigned short* __restrict__ Wieb)
{
    __shared__ float At[KC][TE + 4];
    __shared__ float Wt[KC][WP];

    const int  t    = threadIdx.x;
    const long base = (long)blockIdx.x * TE;
    const int  se  = t >> 2;
    const int  skq = t & 3;
    const long gn  = base + se;
    const long gnc = (gn < N_NODES) ? gn : 0;
    const float* xrow = x + gnc * HD;
    const int tr = t >> 4, tc = t & 15;

    if (blockIdx.x == 0 && t < HD) {
        const float* wr = Wi + (long)t * K1 + HD;
        unsigned short* wo = Wieb + t * 16;
        #pragma unroll
        for (int k = 0; k < 16; ++k) wo[k] = (k < BD) ? f2b(wr[k]) : (unsigned short)0;
    }

    float acc[4][10];
    #pragma unroll
    for (int i = 0; i < 4; ++i)
        #pragma unroll
        for (int j = 0; j < 10; ++j) acc[i][j] = 0.f;

    for (int c = 0; c < NC2; ++c) {
        const int k0 = c * KC;
        __syncthreads();
        {
            const float4 v = *(const float4*)(xrow + k0 + skq * 4);
            At[skq * 4 + 0][se] = v.x;
            At[skq * 4 + 1][se] = v.y;
            At[skq * 4 + 2][se] = v.z;
            At[skq * 4 + 3][se] = v.w;
        }
        for (int i = t; i < HD * KC; i += 256) {
            const int kk = i & (KC - 1);
            const int h  = i >> 4;
            Wt[kk][h] = Wi[h * K1 + k0 + kk];
        }
        __syncthreads();
        gemm_chunk(acc, At, Wt, tr, tc);
    }
    #pragma unroll
    for (int i = 0; i < 4; ++i) {
        const long n = base + tr * 4 + i;
        if (n >= N_NODES) break;
        unsigned short* pp = Pb + n * HD + tc * 10;
        #pragma unroll
        for (int j = 0; j < 10; j += 2) {
            const float v0 = acc[i][j]     + bi[tc * 10 + j];
            const float v1 = acc[i][j + 1] + bi[tc * 10 + j + 1];
            *(ushort2*)(pp + j) = make_ushort2(f2b(v0), f2b(v1));
        }
    }
}

// ============================ H0 (MFMA, no LDS) ============================
// Hb[e] = bf16(relu(Pb[src[e]] + ea[e] @ Wi_e^T)), 16 edges/wave.
// P-term via identity-MFMA transpose of vector-loaded Pb rows; store via
// second identity-MFMA transpose -> 10x ushort4 stores.
__global__ __launch_bounds__(512, 4)
void k_h0m(const float* __restrict__ ea, const int* __restrict__ src,
           const unsigned short* __restrict__ Wieb,
           const unsigned short* __restrict__ Pb,
           unsigned short* __restrict__ Hb)
{
    const int  t    = threadIdx.x;
    const int  w    = t >> 6;
    const int  lane = t & 63;
    const int  cl   = lane & 15;
    const int  kq   = lane >> 4;
    const long base = (long)blockIdx.x * TM + w * 16;

    const long eA  = base + cl;
    const long eAs = (eA < E_EDGES) ? eA : 0;
    const int  sA  = src[eAs];

    // identity B-frag: B[k][col] = (k==col)
    v4s bqI;
    #pragma unroll
    for (int j = 0; j < 4; ++j)
        bqI[j] = (short)((kq * 4 + j == cl) ? 0x3F80 : 0);

    // A-frag from ea row (k' = kq*4+j; guard k' < BD without OOB reads)
    v4s aq;
    {
        const float* earow = ea + eAs * BD;
        if (kq < 3) {
            #pragma unroll
            for (int j = 0; j < 4; ++j) aq[j] = (short)f2b(earow[kq * 4 + j]);
        } else {
            aq[0] = (short)f2b(earow[12]);
            aq[1] = (short)f2b(earow[13]);
            aq[2] = 0; aq[3] = 0;
        }
    }

    // vector loads: P row of this lane's edge (A-layout) + Wieb frags
    const unsigned short* pbrow = Pb + (long)sA * HD;
    v4s pbA[10], bqa[10];
    #pragma unroll
    for (int n = 0; n < 10; ++n) {
        pbA[n] = *(const v4s*)(pbrow + n * 16 + kq * 4);
        bqa[n] = *(const v4s*)&Wieb[(n * 16 + cl) * 16 + kq * 4];
    }

    const bool rowok = (base + cl) < E_EDGES;
    unsigned short* strow = Hb + (base + cl) * HD;

    #pragma unroll
    for (int n = 0; n < 10; ++n) {
        // t = P^T (identity) then += Q
        v4f tv = __builtin_amdgcn_mfma_f32_16x16x16bf16_1k(
                     pbA[n], bqI, (v4f){0.f, 0.f, 0.f, 0.f}, 0, 0, 0);
        tv = __builtin_amdgcn_mfma_f32_16x16x16bf16_1k(aq, bqa[n], tv, 0, 0, 0);
        v4s a2;
        #pragma unroll
        for (int rr = 0; rr < 4; ++rr) {
            float v = tv[rr];
            v = v > 0.f ? v : 0.f;
            a2[rr] = (short)f2b(v);
        }
        const v4f st = __builtin_amdgcn_mfma_f32_16x16x16bf16_1k(
                           a2, bqI, (v4f){0.f, 0.f, 0.f, 0.f}, 0, 0, 0);
        if (rowok) {
            ushort4 o = make_ushort4(f2bt(st[0]), f2bt(st[1]), f2bt(st[2]), f2bt(st[3]));
            *(ushort4*)(strow + n * 16 + kq * 4) = o;
        }
    }
}

// ============================ segment sum ==================================
// FINAL=0: write bf16 Sb. FINAL=1: write fp32 S with sum==0 -> x fallback.
// 8x main unroll (24 in-flight rows) + 4/2/1 tails.
template <int FINAL>
__global__ void k_segb(const unsigned short* __restrict__ Hb,
                       const int* __restrict__ ptr, const int* __restrict__ eid,
                       const float* __restrict__ x,
                       unsigned short* __restrict__ Sb, float* __restrict__ S)
{
    const int  lane = threadIdx.x & 63;
    const int  w    = threadIdx.x >> 6;
    const long n    = (long)blockIdx.x * 4 + w;
    if (n >= N_NODES) return;
    const int p0 = ptr[n], p1 = ptr[n + 1];
    float a0 = 0.f, a1 = 0.f, a2 = 0.f;
    float b0 = 0.f, b1 = 0.f, b2 = 0.f;
    float c0 = 0.f, c1 = 0.f, c2 = 0.f;
    float d0 = 0.f, d1 = 0.f, d2 = 0.f;
    int i = p0;
    for (; i + 8 <= p1; i += 8) {
        const unsigned short* r0 = Hb + (long)eid[i]     * HD;
        const unsigned short* r1 = Hb + (long)eid[i + 1] * HD;
        const unsigned short* r2 = Hb + (long)eid[i + 2] * HD;
        const unsigned short* r3 = Hb + (long)eid[i + 3] * HD;
        const unsigned short* r4 = Hb + (long)eid[i + 4] * HD;
        const unsigned short* r5 = Hb + (long)eid[i + 5] * HD;
        const unsigned short* r6 = Hb + (long)eid[i + 6] * HD;
        const unsigned short* r7 = Hb + (long)eid[i + 7] * HD;
        a0 += b2f(r0[lane]); b0 += b2f(r1[lane]);
        c0 += b2f(r2[lane]); d0 += b2f(r3[lane]);
        a0 += b2f(r4[lane]); b0 += b2f(r5[lane]);
        c0 += b2f(r6[lane]); d0 += b2f(r7[lane]);
        a1 += b2f(r0[64 + lane]); b1 += b2f(r1[64 + lane]);
        c1 += b2f(r2[64 + lane]); d1 += b2f(r3[64 + lane]);
        a1 += b2f(r4[64 + lane]); b1 += b2f(r5[64 + lane]);
        c1 += b2f(r6[64 + lane]); d1 += b2f(r7[64 + lane]);
        if (lane < 32) {
            a2 += b2f(r0[128 + lane]); b2 += b2f(r1[128 + lane]);
            c2 += b2f(r2[128 + lane]); d2 += b2f(r3[128 + lane]);
            a2 += b2f(r4[128 + lane]); b2 += b2f(r5[128 + lane]);
            c2 += b2f(r6[128 + lane]); d2 += b2f(r7[128 + lane]);
        }
    }
    for (; i + 4 <= p1; i += 4) {
        const unsigned short* r0 = Hb + (long)eid[i]     * HD;
        const unsigned short* r1 = Hb + (long)eid[i + 1] * HD;
        const unsigned short* r2 = Hb + (long)eid[i + 2] * HD;
        const unsigned short* r3 = Hb + (long)eid[i + 3] * HD;
        a0 += b2f(r0[lane]); b0 += b2f(r1[lane]);
        c0 += b2f(r2[lane]); d0 += b2f(r3[lane]);
        a1 += b2f(r0[64 + lane]); b1 += b2f(r1[64 + lane]);
        c1 += b2f(r2[64 + lane]); d1 += b2f(r3[64 + lane]);
        if (lane < 32) {
            a2 += b2f(r0[128 + lane]); b2 += b2f(r1[128 + lane]);
            c2 += b2f(r2[128 + lane]); d2 += b2f(r3[128 + lane]);
        }
    }
    for (; i + 2 <= p1; i += 2) {
        const unsigned short* r0 = Hb + (long)eid[i]     * HD;
        const unsigned short* r1 = Hb + (long)eid[i + 1] * HD;
        a0 += b2f(r0[lane]); b0 += b2f(r1[lane]);
        a1 += b2f(r0[64 + lane]); b1 += b2f(r1[64 + lane]);
        if (lane < 32) {
            a2 += b2f(r0[128 + lane]); b2 += b2f(r1[128 + lane]);
        }
    }
    if (i < p1) {
        const unsigned short* r0 = Hb + (long)eid[i] * HD;
        a0 += b2f(r0[lane]);
        a1 += b2f(r0[64 + lane]);
        if (lane < 32) a2 += b2f(r0[128 + lane]);
    }
    a0 += b0 + c0 + d0;
    a1 += b1 + c1 + d1;
    a2 += b2 + c2 + d2;

    const long sb = n * HD;
    if (FINAL) {
        float s = a0 + a1 + a2;
        #pragma unroll
        for (int off = 32; off > 0; off >>= 1) s += __shfl_xor(s, off, 64);
        if (s == 0.f) {
            S[sb + lane]      = x[sb + lane];
            S[sb + 64 + lane] = x[sb + 64 + lane];
            if (lane < 32) S[sb + 128 + lane] = x[sb + 128 + lane];
            return;
        }
        S[sb + lane]      = a0;
        S[sb + 64 + lane] = a1;
        if (lane < 32) S[sb + 128 + lane] = a2;
    } else {
        Sb[sb + lane]      = f2b(a0);
        Sb[sb + 64 + lane] = f2b(a1);
        if (lane < 32) Sb[sb + 128 + lane] = f2b(a2);
    }
}

// ============================ MFMA update, iter 1 ==========================
// Hb[e] = bf16(relu(Hb[e] + Wh @ (Sb[src[e]] - Hb[e^1]) + bh))
// (Hb still holds H0 = h0.)  h0 added via identity-MFMA of vector-loaded
// own rows; store via identity-MFMA transpose -> 10x ushort4.
__global__ __launch_bounds__(512, 4)
void k_updm1(const unsigned short* __restrict__ Sb,
             const int* __restrict__ src,
             const unsigned short* __restrict__ Whb, const float* __restrict__ bh,
             unsigned short* __restrict__ Hb)
{
    __shared__ unsigned short Whl[HD * WHP];   // 52480 B, [h][k] bf16

    const int t = threadIdx.x;
    for (int i = t * 4; i < HD * WHP; i += 2048)
        *(ushort4*)&Whl[i] = *(const ushort4*)&Whb[i];
    __syncthreads();

    const int  w    = t >> 6;
    const int  lane = t & 63;
    const int  cl   = lane & 15;     // A-row / B-col / C-col selector
    const int  kq   = lane >> 4;     // k-group 0..3
    const long base = (long)blockIdx.x * TM + w * 16;

    const long eA  = base + cl;
    const long eAs = (eA < E_EDGES) ? eA : 0;
    const int  sA  = src[eAs];
    const unsigned short* sbrow = Sb + (long)sA * HD + kq * 4;
    const unsigned short* rvrow = Hb + (eAs ^ 1) * HD + kq * 4;

    // identity B-frag
    v4s bqI;
    #pragma unroll
    for (int j = 0; j < 4; ++j)
        bqI[j] = (short)((kq * 4 + j == cl) ? 0x3F80 : 0);

    // full-depth prefetch: issue all 20 loads, waits resolve incrementally
    ushort4 ps[10], pr[10];
    #pragma unroll
    for (int c = 0; c < 10; ++c) {
        ps[c] = *(const ushort4*)(sbrow + c * KC);
        pr[c] = *(const ushort4*)(rvrow + c * KC);
    }

    v4f acc[10];
    #pragma unroll
    for (int n = 0; n < 10; ++n) acc[n] = (v4f){0.f, 0.f, 0.f, 0.f};

    #pragma unroll
    for (int c = 0; c < 10; ++c) {
        const v4s a = mdiff(ps[c], pr[c]);
        #pragma unroll
        for (int n = 0; n < 10; ++n) {
            const v4s b = *(const v4s*)&Whl[(n * 16 + cl) * WHP + c * KC + kq * 4];
            acc[n] = __builtin_amdgcn_mfma_f32_16x16x16bf16_1k(a, b, acc[n], 0, 0, 0);
        }
    }

    // ---- epilogue: h0 via identity-MFMA of own rows (vector loads) ----
    const unsigned short* ownrow = Hb + eAs * HD;
    v4s h0A[10];
    #pragma unroll
    for (int n = 0; n < 10; ++n)
        h0A[n] = *(const v4s*)(ownrow + n * 16 + kq * 4);
    #pragma unroll
    for (int n = 0; n < 10; ++n)
        acc[n] = __builtin_amdgcn_mfma_f32_16x16x16bf16_1k(h0A[n], bqI, acc[n], 0, 0, 0);

    const bool rowok = (base + cl) < E_EDGES;
    unsigned short* strow = Hb + (base + cl) * HD;

    #pragma unroll
    for (int n = 0; n < 10; ++n) {
        const int col = n * 16 + cl;
        const float bb = bh[col];
        v4s a2;
        #pragma unroll
        for (int rr = 0; rr < 4; ++rr) {
            float v = acc[n][rr] + bb;
            v = v > 0.f ? v : 0.f;
            a2[rr] = (short)f2b(v);
        }
        const v4f st = __builtin_amdgcn_mfma_f32_16x16x16bf16_1k(
                           a2, bqI, (v4f){0.f, 0.f, 0.f, 0.f}, 0, 0, 0);
        if (rowok) {
            ushort4 o = make_ushort4(f2bt(st[0]), f2bt(st[1]), f2bt(st[2]), f2bt(st[3]));
            *(ushort4*)(strow + n * 16 + kq * 4) = o;
        }
    }
}

// ============================ MFMA update, iter 2 ==========================
// DEFERRED-h0: Wh K-loop first, then epilogue: P via identity-MFMA of
// vector-loaded Pb rows (reuses sA), Q chained on top, fused relu, store
// via identity-MFMA transpose -> 10x ushort4.
__global__ __launch_bounds__(512, 4)
void k_updm2(const unsigned short* __restrict__ Sb,
             const float* __restrict__ ea, const int* __restrict__ src,
             const unsigned short* __restrict__ Wieb,
             const unsigned short* __restrict__ Whb, const float* __restrict__ bh,
             const unsigned short* __restrict__ Pb,
             unsigned short* __restrict__ Hb)
{
    __shared__ unsigned short Whl[HD * WHP];    // 52480 B

    const int t = threadIdx.x;
    for (int i = t * 4; i < HD * WHP; i += 2048)
        *(ushort4*)&Whl[i] = *(const ushort4*)&Whb[i];
    __syncthreads();

    const int  w    = t >> 6;
    const int  lane = t & 63;
    const int  cl   = lane & 15;
    const int  kq   = lane >> 4;
    const long base = (long)blockIdx.x * TM + w * 16;

    const long eA  = base + cl;
    const long eAs = (eA < E_EDGES) ? eA : 0;
    const int  sA  = src[eAs];
    const unsigned short* sbrow = Sb + (long)sA * HD + kq * 4;
    const unsigned short* rvrow = Hb + (eAs ^ 1) * HD + kq * 4;

    // identity B-frag
    v4s bqI;
    #pragma unroll
    for (int j = 0; j < 4; ++j)
        bqI[j] = (short)((kq * 4 + j == cl) ? 0x3F80 : 0);

    // full-depth prefetch of both gather streams
    ushort4 ps[10], pr[10];
    #pragma unroll
    for (int c = 0; c < 10; ++c) {
        ps[c] = *(const ushort4*)(sbrow + c * KC);
        pr[c] = *(const ushort4*)(rvrow + c * KC);
    }

    v4f acc[10];
    #pragma unroll
    for (int n = 0; n < 10; ++n) acc[n] = (v4f){0.f, 0.f, 0.f, 0.f};

    #pragma unroll
    for (int c = 0; c < 10; ++c) {
        const v4s a = mdiff(ps[c], pr[c]);
        #pragma unroll
        for (int n = 0; n < 10; ++n) {
            const v4s b = *(const v4s*)&Whl[(n * 16 + cl) * WHP + c * KC + kq * 4];
            acc[n] = __builtin_amdgcn_mfma_f32_16x16x16bf16_1k(a, b, acc[n], 0, 0, 0);
        }
    }
    // All rev-row (Hb) reads issued above; stores below are same-wave ordered.

    // ---- epilogue: aq + P-row vector loads + Wieb frags ----
    v4s aq;
    {
        const float* earow = ea + eAs * BD;
        if (kq < 3) {
            #pragma unroll
            for (int j = 0; j < 4; ++j) aq[j] = (short)f2b(earow[kq * 4 + j]);
        } else {
            aq[0] = (short)f2b(earow[12]);
            aq[1] = (short)f2b(earow[13]);
            aq[2] = 0; aq[3] = 0;
        }
    }
    const unsigned short* pbrow = Pb + (long)sA * HD;
    v4s pbA[10], bqa[10];
    #pragma unroll
    for (int n = 0; n < 10; ++n) {
        pbA[n] = *(const v4s*)(pbrow + n * 16 + kq * 4);
        bqa[n] = *(const v4s*)&Wieb[(n * 16 + cl) * 16 + kq * 4];
    }

    const bool rowok = (base + cl) < E_EDGES;
    unsigned short* strow = Hb + (base + cl) * HD;

    #pragma unroll
    for (int n = 0; n < 10; ++n) {
        // t = P^T + Q
        v4f tv = __builtin_amdgcn_mfma_f32_16x16x16bf16_1k(
                     pbA[n], bqI, (v4f){0.f, 0.f, 0.f, 0.f}, 0, 0, 0);
        tv = __builtin_amdgcn_mfma_f32_16x16x16bf16_1k(aq, bqa[n], tv, 0, 0, 0);
        const int col = n * 16 + cl;
        const float bb = bh[col];
        v4s a2;
        #pragma unroll
        for (int rr = 0; rr < 4; ++rr) {
            float h0 = tv[rr];
            h0 = h0 > 0.f ? h0 : 0.f;
            float v = h0 + acc[n][rr] + bb;
            v = v > 0.f ? v : 0.f;
            a2[rr] = (short)f2b(v);
        }
        const v4f st = __builtin_amdgcn_mfma_f32_16x16x16bf16_1k(
                           a2, bqI, (v4f){0.f, 0.f, 0.f, 0.f}, 0, 0, 0);
        if (rowok) {
            ushort4 o = make_ushort4(f2bt(st[0]), f2bt(st[1]), f2bt(st[2]), f2bt(st[3]));
            *(ushort4*)(strow + n * 16 + kq * 4) = o;
        }
    }
}

// ============================ output =======================================
__global__ __launch_bounds__(256, 3)
void k_out(const float* __restrict__ x, const float* __restrict__ Mg,
           const float* __restrict__ Wo, const float* __restrict__ bo,
           float* __restrict__ out)
{
    __shared__ float At[KC][TE + 4];
    __shared__ float Wt[KC][WP];

    const int  t    = threadIdx.x;
    const long base = (long)blockIdx.x * TE;
    const int  se  = t >> 2;
    const int  skq = t & 3;
    const long gn  = base + se;
    const bool ev  = gn < N_NODES;
    const long gnc = ev ? gn : 0;
    const float* xrow = x  + gnc * HD;
    const float* mrow = Mg + gnc * HD;
    const int tr = t >> 4, tc = t & 15;

    float acc[4][10];
    #pragma unroll
    for (int i = 0; i < 4; ++i)
        #pragma unroll
        for (int j = 0; j < 10; ++j) acc[i][j] = 0.f;

    for (int c = 0; c < KO / KC; ++c) {
        const int k0 = c * KC;
        __syncthreads();
        {
            const int kb = k0 + skq * 4;
            const float4 v = (kb < HD) ? *(const float4*)(xrow + kb)
                                       : *(const float4*)(mrow + (kb - HD));
            At[skq * 4 + 0][se] = v.x;
            At[skq * 4 + 1][se] = v.y;
            At[skq * 4 + 2][se] = v.z;
            At[skq * 4 + 3][se] = v.w;
        }
        for (int i = t; i < HD * KC; i += 256) {
            const int kk = i & (KC - 1);
            const int h  = i >> 4;
            Wt[kk][h] = Wo[h * KO + k0 + kk];
        }
        __syncthreads();
        gemm_chunk(acc, At, Wt, tr, tc);
    }
    #pragma unroll
    for (int i = 0; i < 4; ++i) {
        const long n = base + tr * 4 + i;
        if (n >= N_NODES) break;
        float* op = out + n * HD + tc * 10;
        #pragma unroll
        for (int j = 0; j < 10; j += 2) {
            float v0 = acc[i][j]     + bo[tc * 10 + j];
            float v1 = acc[i][j + 1] + bo[tc * 10 + j + 1];
            v0 = v0 > 0.f ? v0 : 0.f;
            v1 = v1 > 0.f ? v1 : 0.f;
            *(float2*)(op + j) = make_float2(v0, v1);
        }
    }
}

// ---------------------------------------------------------------------------
extern "C" void kernel_launch(void* const* d_in, const int* in_sizes, int n_in,
                              void* d_out, int out_size, void* d_ws, size_t ws_size,
                              hipStream_t stream)
{
    const float* x  = (const float*)d_in[0];
    const float* ea = (const float*)d_in[1];
    const int*   ei = (const int*)d_in[2];
    const float* Wi = (const float*)d_in[4];
    const float* bi = (const float*)d_in[5];
    const float* Wh = (const float*)d_in[6];
    const float* bh = (const float*)d_in[7];
    const float* Wo = (const float*)d_in[8];
    const float* bo = (const float*)d_in[9];
    float* out = (float*)d_out;

    const int* src = ei;
    const int* dst = ei + E_EDGES;

    const int gM  = (E_EDGES + TM - 1) / TM;      // 3907
    const int gN  = (N_NODES + TE - 1) / TE;      // 782
    const int gF  = (N_NODES + 3) / 4;            // 12500
    const int gEe = (E_EDGES + 255) / 256;        // 1954

    // ws: Hb bf16 (160e6) | Mf fp32 (32e6) | CSR (~2.6e6) | Wieb | Whb
    char* w = (char*)d_ws;
    unsigned short* Hb  = (unsigned short*)(w);
    float* Mf   = (float*)(w + 160000000);
    int*   ptr  = (int*)  (w + 192000000);
    int*   cnt  = (int*)  (w + 192200016);
    int*   cur  = (int*)  (w + 192400016);
    int*   eid  = (int*)  (w + 192600016);
    unsigned short* Wieb = (unsigned short*)(w + 194600064);
    unsigned short* Whb  = (unsigned short*)(w + 194605184);
    // d_out hosts Pb (16e6) + Sb (16e6) until k_out.
    unsigned short* Pb = (unsigned short*)d_out;
    unsigned short* Sb = (unsigned short*)((char*)d_out + 16000000);

    k_zero<<<(100000 + 1023) / 1024, 256, 0, stream>>>((float*)cnt, 100000);
    k_csr_count<<<gEe, 256, 0, stream>>>(dst, cnt);
    k_wcvt<<<25, 256, 0, stream>>>(Wh, Whb);
    k_csr_scan<<<1, 1024, 0, stream>>>(cnt, ptr);
    k_csr_fill<<<gEe, 256, 0, stream>>>(dst, ptr, cur, eid);

    k_nodeproj<<<gN, 256, 0, stream>>>(x, Wi, bi, Pb, Wieb);
    k_h0m<<<gM, 512, 0, stream>>>(ea, src, Wieb, Pb, Hb);                 // H0
    k_segb<0><<<gF, 256, 0, stream>>>(Hb, ptr, eid, x, Sb, nullptr);      // S0
    k_updm1<<<gM, 512, 0, stream>>>(Sb, src, Whb, bh, Hb);                // H1
    k_segb<0><<<gF, 256, 0, stream>>>(Hb, ptr, eid, x, Sb, nullptr);      // S1
    k_updm2<<<gM, 512, 0, stream>>>(Sb, ea, src, Wieb, Whb, bh, Pb, Hb);  // H2
    k_segb<1><<<gF, 256, 0, stream>>>(Hb, ptr, eid, x, nullptr, Mf);      // M
    k_out<<<gN, 256, 0, stream>>>(x, Mf, Wo, bo, out);
}